// Round 6
// baseline (1029.525 us; speedup 1.0000x reference)
//
#include <hip/hip_runtime.h>
#include <hip/hip_bf16.h>
#include <math.h>

// Problem constants (match reference)
#define N_NODES 50000
#define N_EDGES 800000
#define DIN     64
#define HID     128
#define HEADS   4
#define NGRAPH  64
#define NCLS    8
#define EPSB    1e-5f
#define SLOPE   0.2f
#define PSEG    16               // pooling segments per graph
#define MAXC    256              // gat_agg edge-chunk per head

#define MPAD    (N_NODES + 64)   // row padding for 64-row GEMM tiles

typedef __hip_bfloat16 bf16;
typedef __attribute__((ext_vector_type(8))) short short8;
typedef __attribute__((ext_vector_type(4))) float f32x4;

__device__ __forceinline__ float b2f(bf16 v) { return __bfloat162float(v); }
__device__ __forceinline__ bf16  f2b(float v) { return __float2bfloat16(v); }
__device__ __forceinline__ float lo_f(unsigned v) {
    unsigned u = v << 16; return __builtin_bit_cast(float, u);
}
__device__ __forceinline__ float hi_f(unsigned v) {
    unsigned u = v & 0xffff0000u; return __builtin_bit_cast(float, u);
}

// ---------------- CSR build ----------------
__global__ void k_count(const int* __restrict__ ei, int* __restrict__ deg) {
    int e = blockIdx.x * 256 + threadIdx.x;
    if (e < N_EDGES) atomicAdd(&deg[ei[N_EDGES + e]], 1);
}

__global__ void k_scan(const int* __restrict__ deg, int* __restrict__ row_off) {
    __shared__ int sm[1024];
    int carry = 0;
    if (threadIdx.x == 0) row_off[0] = 0;
    for (int base = 0; base < N_NODES; base += 1024) {
        int i = base + threadIdx.x;
        int v = (i < N_NODES) ? deg[i] : 0;
        sm[threadIdx.x] = v;
        __syncthreads();
        for (int off = 1; off < 1024; off <<= 1) {
            int t = (threadIdx.x >= off) ? sm[threadIdx.x - off] : 0;
            __syncthreads();
            sm[threadIdx.x] += t;
            __syncthreads();
        }
        if (i < N_NODES) row_off[i + 1] = carry + sm[threadIdx.x];
        int tot = sm[1023];
        __syncthreads();
        carry += tot;
    }
}

__global__ void k_fill(const int* __restrict__ ei, const int* __restrict__ row_off,
                       int* __restrict__ cursor, int* __restrict__ col) {
    int e = blockIdx.x * 256 + threadIdx.x;
    if (e < N_EDGES) {
        int s = ei[e], d = ei[N_EDGES + e];
        int pos = atomicAdd(&cursor[d], 1);
        col[row_off[d] + pos] = s;
    }
}

// per-graph start offsets from sorted batch
__global__ void k_bounds(const int* __restrict__ batch, int* __restrict__ gstart) {
    int i = blockIdx.x * 256 + threadIdx.x;
    if (i >= N_NODES) return;
    int b = batch[i];
    int prev = (i == 0) ? -1 : batch[i - 1];
    for (int g = prev + 1; g <= b; ++g) gstart[g] = i;
    if (i == N_NODES - 1)
        for (int g = b + 1; g <= NGRAPH; ++g) gstart[g] = N_NODES;
}

// ---------------- weight prep: convert to bf16, transposed (Bt[n][k]) ----------------
__global__ void k_prep(const float* __restrict__ s0Wl, const float* __restrict__ s0Wr,
                       const float* __restrict__ s1Wl, const float* __restrict__ s1Wr,
                       const float* __restrict__ g0W,  const float* __restrict__ g1W,
                       const float* __restrict__ idpW,
                       bf16* __restrict__ s0t, bf16* __restrict__ s1t,
                       bf16* __restrict__ g0t, bf16* __restrict__ g1t,
                       bf16* __restrict__ idpt) {
    int t = blockIdx.x * 256 + threadIdx.x;
    if (t < 16384) { int n = t >> 7, k = t & 127;
        s0t[t] = f2b(k < 64 ? s0Wl[k * 128 + n] : s0Wr[(k - 64) * 128 + n]); return; }
    t -= 16384;
    if (t < 32768) { int n = t >> 8, k = t & 255;
        s1t[t] = f2b(k < 128 ? s1Wl[k * 128 + n] : s1Wr[(k - 128) * 128 + n]); return; }
    t -= 32768;
    if (t < 65536) { int n = t >> 7, k = t & 127; g0t[t] = f2b(g0W[k * 512 + n]); return; }
    t -= 65536;
    if (t < 65536) { int n = t >> 7, k = t & 127; g1t[t] = f2b(g1W[k * 512 + n]); return; }
    t -= 65536;
    if (t < 49152) { int l = t >> 14, r = t & 16383; int n = r >> 7, k = r & 127;
        idpt[t] = f2b(idpW[l * 16384 + k * 128 + n]); }
}

// ---------------- SAGE mean-aggregate + concat self features ----------------
__global__ void k_sage_agg_f32(const float* __restrict__ xin, const int* __restrict__ row_off,
                               const int* __restrict__ col, bf16* __restrict__ acat) {
    int i = blockIdx.x;
    int c = threadIdx.x;  // 64
    int s0 = row_off[i], s1 = row_off[i + 1];
    float acc = 0.f;
    for (int j = s0; j < s1; ++j)
        acc += xin[(size_t)col[j] * DIN + c];
    acat[(size_t)i * (2 * DIN) + c]       = f2b(acc / fmaxf((float)(s1 - s0), 1.0f));
    acat[(size_t)i * (2 * DIN) + DIN + c] = f2b(xin[(size_t)i * DIN + c]);
}

__global__ void k_sage_agg_bf(const bf16* __restrict__ xin, const int* __restrict__ row_off,
                              const int* __restrict__ col, bf16* __restrict__ acat) {
    int i = blockIdx.x;
    int c = threadIdx.x;  // 64 lanes, channels 2c,2c+1
    int s0 = row_off[i], s1 = row_off[i + 1];
    const unsigned* xb = (const unsigned*)xin;
    float a0 = 0.f, a1 = 0.f;
    for (int j = s0; j < s1; ++j) {
        unsigned v = xb[(size_t)col[j] * (HID / 2) + c];
        a0 += lo_f(v); a1 += hi_f(v);
    }
    float inv = 1.0f / fmaxf((float)(s1 - s0), 1.0f);
    acat[(size_t)i * (2 * HID) + 2 * c]     = f2b(a0 * inv);
    acat[(size_t)i * (2 * HID) + 2 * c + 1] = f2b(a1 * inv);
    ((unsigned*)acat)[(size_t)i * HID + (HID / 2) + c] = xb[(size_t)i * (HID / 2) + c];
}

// ---------------- MFMA GEMM: C[M x Nc] = A[M x K] @ Bt^T, fused epilogue ----------------
// EPI: 0=none  1=bias+BN+PReLU  2=bias+PReLU  3=bias
template <int K, int NT, int EPI>
__global__ __launch_bounds__(256) void k_gemm(
        const bf16* __restrict__ A, const bf16* __restrict__ Bt, bf16* __restrict__ C,
        int M, int Nc,
        const float* __restrict__ bias, const float* __restrict__ bng,
        const float* __restrict__ bnb,  const float* __restrict__ bnm,
        const float* __restrict__ bnv,  const float* __restrict__ pa) {
    int wave = threadIdx.x >> 6, lane = threadIdx.x & 63;
    int ln = lane & 15, q = lane >> 4;
    int m0 = blockIdx.x * 64 + wave * 16;
    int n0 = blockIdx.y * (NT * 16);
    const bf16* arow = A + (size_t)(m0 + ln) * K + q * 8;

    f32x4 acc[NT];
#pragma unroll
    for (int t = 0; t < NT; ++t) acc[t] = (f32x4){0.f, 0.f, 0.f, 0.f};

#pragma unroll
    for (int k = 0; k < K; k += 32) {
        short8 a = *(const short8*)(const void*)(arow + k);
#pragma unroll
        for (int t = 0; t < NT; ++t) {
            short8 b = *(const short8*)(const void*)(Bt + (size_t)(n0 + t * 16 + ln) * K + k + q * 8);
            acc[t] = __builtin_amdgcn_mfma_f32_16x16x32_bf16(a, b, acc[t], 0, 0, 0);
        }
    }

#pragma unroll
    for (int t = 0; t < NT; ++t) {
        int cidx = n0 + t * 16 + ln;
        float bi = 0.f, g = 1.f, bb = 0.f, mm = 0.f, iv = 1.f, al = 1.f;
        if (EPI >= 1) bi = bias[cidx];
        if (EPI == 1) { g = bng[cidx]; bb = bnb[cidx]; mm = bnm[cidx]; iv = rsqrtf(bnv[cidx] + EPSB); }
        if (EPI == 1 || EPI == 2) al = pa[cidx];
#pragma unroll
        for (int r = 0; r < 4; ++r) {
            int mr = m0 + q * 4 + r;
            if (mr < M) {
                float v = acc[t][r] + bi;
                if (EPI == 1) v = (v - mm) * iv * g + bb;
                if (EPI == 1 || EPI == 2) v = v >= 0.f ? v : al * v;
                C[(size_t)mr * Nc + cidx] = f2b(v);
            }
        }
    }
}

// ---------------- GAT ----------------
__global__ void k_gat_scores(const bf16* __restrict__ xw, const float* __restrict__ as,
                             const float* __restrict__ ad,
                             float* __restrict__ es, float* __restrict__ ed) {
    int wid = (blockIdx.x * 256 + threadIdx.x) >> 6;
    int lane = threadIdx.x & 63;
    if (wid >= N_NODES * HEADS) return;
    int i = wid / HEADS, h = wid % HEADS;
    const bf16* row = xw + (size_t)i * (HEADS * HID) + h * HID;
    float v0 = b2f(row[lane]), v1 = b2f(row[lane + 64]);
    float s1 = v0 * as[h * HID + lane] + v1 * as[h * HID + lane + 64];
    float s2 = v0 * ad[h * HID + lane] + v1 * ad[h * HID + lane + 64];
    for (int off = 32; off; off >>= 1) {
        s1 += __shfl_down(s1, off, 64);
        s2 += __shfl_down(s2, off, 64);
    }
    if (lane == 0) { es[i * HEADS + h] = s1; ed[i * HEADS + h] = s2; }
}

// Per-node GAT aggregation: wave w = head w.
// No max-subtraction: softmax is shift-invariant and scores are bounded (|e|~3
// with 0.05-scale weights), so exp() cannot overflow — ratio is identical.
// Phase A: lane-parallel exp scores (expf for precision) into per-wave LDS.
// Phase B: 2 edges/iteration — half-wave 0 -> edge e, half-wave 1 -> edge e+1,
//          uint2 (8B) gathers, 4 channel-accumulators/lane, shfl_xor(32) merge.
__global__ __launch_bounds__(256) void k_gat_agg(
        const bf16* __restrict__ xw, const float* __restrict__ es,
        const float* __restrict__ ed, const int* __restrict__ row_off,
        const int* __restrict__ col, const float* __restrict__ bias,
        const float* __restrict__ bng, const float* __restrict__ bnb,
        const float* __restrict__ bnm, const float* __restrict__ bnv,
        const float* __restrict__ pa,
        bf16* __restrict__ out) {
    __shared__ float sEx[HEADS][MAXC];
    __shared__ int   sCol[HEADS][MAXC];
    __shared__ float sO[HEADS][HID];
    int i = blockIdx.x;
    int w = threadIdx.x >> 6;   // head
    int lane = threadIdx.x & 63;
    int sub = lane >> 5, sl = lane & 31;
    int s0 = row_off[i], s1 = row_off[i + 1];
    float edi = ed[i * HEADS + w];
    float esi = es[i * HEADS + w];
    const uint2* xw2 = (const uint2*)xw;   // row stride HEADS*HID/4 = 128 uint2

    float den = 0.f;
    float a0 = 0.f, a1 = 0.f, a2 = 0.f, a3 = 0.f;

    {   // self loop (half-wave 0 does the feature work)
        float e = esi + edi;
        e = e >= 0.f ? e : SLOPE * e;
        float ex = expf(e);
        if (lane == 0) den += ex;
        if (sub == 0) {
            uint2 v = xw2[(size_t)i * 128 + w * 32 + sl];
            a0 += ex * lo_f(v.x); a1 += ex * hi_f(v.x);
            a2 += ex * lo_f(v.y); a3 += ex * hi_f(v.y);
        }
    }
    for (int c0 = s0; c0 < s1; c0 += MAXC) {
        int cnt = min(MAXC, s1 - c0);
        // phase A: per-edge exp scores (one lane per edge)
        for (int l = lane; l < cnt; l += 64) {
            int s = col[c0 + l];
            float e = es[s * HEADS + w] + edi;
            e = e >= 0.f ? e : SLOPE * e;
            float ex = expf(e);
            den += ex;
            sEx[w][l]  = ex;
            sCol[w][l] = s;
        }
        // same-wave LDS write->read: program order, no block barrier needed
        // phase B: 2 edges per iteration, lanes over features
        for (int e2 = 0; e2 < cnt; e2 += 2) {
            int idx = e2 + sub;
            bool valid = idx < cnt;
            float ex = valid ? sEx[w][idx] : 0.f;
            int s = valid ? sCol[w][idx] : 0;
            uint2 v = xw2[(size_t)s * 128 + w * 32 + sl];
            a0 += ex * lo_f(v.x); a1 += ex * hi_f(v.x);
            a2 += ex * lo_f(v.y); a3 += ex * hi_f(v.y);
        }
    }
    // merge half-waves
    a0 += __shfl_xor(a0, 32, 64);
    a1 += __shfl_xor(a1, 32, 64);
    a2 += __shfl_xor(a2, 32, 64);
    a3 += __shfl_xor(a3, 32, 64);
    for (int off = 32; off; off >>= 1) den += __shfl_down(den, off, 64);
    den = __shfl(den, 0, 64);

    float inv = 1.0f / den;
    if (sub == 0) {
        sO[w][4 * sl + 0] = a0 * inv;
        sO[w][4 * sl + 1] = a1 * inv;
        sO[w][4 * sl + 2] = a2 * inv;
        sO[w][4 * sl + 3] = a3 * inv;
    }
    __syncthreads();
    int j = threadIdx.x;
    if (j < HID) {
        float v = 0.25f * (sO[0][j] + sO[1][j] + sO[2][j] + sO[3][j]) + bias[j];
        float g = bng[j], bb = bnb[j], mm = bnm[j], vv = bnv[j];
        v = (v - mm) * rsqrtf(vv + EPSB) * g + bb;
        float a = pa[j];
        out[(size_t)i * HID + j] = f2b(v >= 0.f ? v : a * v);
    }
}

// ---------------- pool / classifier ----------------
__global__ void k_pool(const bf16* __restrict__ h, const int* __restrict__ gstart,
                       float* __restrict__ pool) {
    int g = blockIdx.x, s = blockIdx.y;
    int c = threadIdx.x;   // 64 lanes, channels 2c,2c+1
    int b0 = gstart[g], b1 = gstart[g + 1];
    int len = b1 - b0;
    if (len <= 0) return;
    int per = (len + PSEG - 1) / PSEG;
    int r0 = b0 + s * per;
    int r1 = min(r0 + per, b1);
    if (r0 >= r1) return;
    const unsigned* hb = (const unsigned*)h;
    float a0 = 0.f, a1 = 0.f;
    for (int i = r0; i < r1; ++i) {
        unsigned v = hb[(size_t)i * (HID / 2) + c];
        a0 += lo_f(v); a1 += hi_f(v);
    }
    atomicAdd(&pool[g * HID + 2 * c], a0);
    atomicAdd(&pool[g * HID + 2 * c + 1], a1);
}

__global__ void k_cls(const float* __restrict__ pool, const int* __restrict__ gstart,
                      const float* __restrict__ W, const float* __restrict__ b,
                      float* __restrict__ out) {
    int t = threadIdx.x;            // 512 = 64*8
    int g = t / NCLS, n = t % NCLS;
    float ic = 1.0f / fmaxf((float)(gstart[g + 1] - gstart[g]), 1.0f);
    float acc = b[n];
    for (int k = 0; k < HID; ++k)
        acc += pool[g * HID + k] * ic * W[k * NCLS + n];
    out[g * NCLS + n] = acc;
}

// ---------------- launch ----------------
extern "C" void kernel_launch(void* const* d_in, const int* in_sizes, int n_in,
                              void* d_out, int out_size, void* d_ws, size_t ws_size,
                              hipStream_t stream) {
    const float* x      = (const float*)d_in[0];
    const int*   ei     = (const int*)d_in[1];
    const int*   batch  = (const int*)d_in[2];
    const float* s0_Wl  = (const float*)d_in[3];
    const float* s0_Wr  = (const float*)d_in[4];
    const float* s0_b   = (const float*)d_in[5];
    const float* s1_Wl  = (const float*)d_in[6];
    const float* s1_Wr  = (const float*)d_in[7];
    const float* s1_b   = (const float*)d_in[8];
    const float* bn_g   = (const float*)d_in[9];
    const float* bn_b   = (const float*)d_in[10];
    const float* bn_m   = (const float*)d_in[11];
    const float* bn_v   = (const float*)d_in[12];
    const float* pre_a  = (const float*)d_in[13];
    const float* g0_W   = (const float*)d_in[14];
    const float* g0_as  = (const float*)d_in[15];
    const float* g0_ad  = (const float*)d_in[16];
    const float* g0_bias= (const float*)d_in[17];
    const float* g1_W   = (const float*)d_in[18];
    const float* g1_as  = (const float*)d_in[19];
    const float* g1_ad  = (const float*)d_in[20];
    const float* g1_bias= (const float*)d_in[21];
    const float* idp_W  = (const float*)d_in[22];
    const float* idp_b  = (const float*)d_in[23];
    const float* idp_a  = (const float*)d_in[24];
    const float* cls_W  = (const float*)d_in[25];
    const float* cls_b  = (const float*)d_in[26];
    float* out = (float*)d_out;

    // workspace carve (256B aligned)
    char* p = (char*)d_ws;
    auto alloc = [&](size_t bytes) -> void* {
        void* r = (void*)p;
        p += (bytes + 255) & ~(size_t)255;
        return r;
    };
    int*   deg     = (int*)alloc((size_t)N_NODES * 4);
    int*   cursor  = (int*)alloc((size_t)N_NODES * 4);
    int*   row_off = (int*)alloc((size_t)(N_NODES + 1) * 4);
    int*   col     = (int*)alloc((size_t)N_EDGES * 4);
    int*   gstart  = (int*)alloc((size_t)(NGRAPH + 1) * 4);
    float* es      = (float*)alloc((size_t)N_NODES * HEADS * 4);
    float* edv     = (float*)alloc((size_t)N_NODES * HEADS * 4);
    float* pool    = (float*)alloc((size_t)NGRAPH * HID * 4);
    bf16*  hA      = (bf16*)alloc((size_t)MPAD * HID * 2);
    bf16*  hB      = (bf16*)alloc((size_t)MPAD * HID * 2);
    // union: acat0 (MPAD*128 bf16), acat1 (MPAD*256 bf16), xw (MPAD*512 bf16)
    bf16*  u       = (bf16*)alloc((size_t)MPAD * (HEADS * HID) * 2);
    bf16*  acat0   = u;
    bf16*  acat1   = u;
    bf16*  xw      = u;
    // bf16 transposed weights
    bf16*  s0t     = (bf16*)alloc((size_t)128 * 128 * 2);
    bf16*  s1t     = (bf16*)alloc((size_t)128 * 256 * 2);
    bf16*  g0t     = (bf16*)alloc((size_t)512 * 128 * 2);
    bf16*  g1t     = (bf16*)alloc((size_t)512 * 128 * 2);
    bf16*  idpt    = (bf16*)alloc((size_t)3 * 128 * 128 * 2);

    hipMemsetAsync(deg, 0, (size_t)N_NODES * 4, stream);
    hipMemsetAsync(cursor, 0, (size_t)N_NODES * 4, stream);
    hipMemsetAsync(pool, 0, (size_t)NGRAPH * HID * 4, stream);

    // weight prep + CSR build + graph bounds
    k_prep<<<(229376 + 255) / 256, 256, 0, stream>>>(s0_Wl, s0_Wr, s1_Wl, s1_Wr,
                                                     g0_W, g1_W, idp_W,
                                                     s0t, s1t, g0t, g1t, idpt);
    k_count<<<(N_EDGES + 255) / 256, 256, 0, stream>>>(ei, deg);
    k_scan<<<1, 1024, 0, stream>>>(deg, row_off);
    k_fill<<<(N_EDGES + 255) / 256, 256, 0, stream>>>(ei, row_off, cursor, col);
    k_bounds<<<(N_NODES + 255) / 256, 256, 0, stream>>>(batch, gstart);

    const int MB = (N_NODES + 63) / 64;   // 782 row-blocks

    // SAGE 0
    k_sage_agg_f32<<<N_NODES, DIN, 0, stream>>>(x, row_off, col, acat0);
    k_gemm<128, 8, 1><<<dim3(MB, 1), 256, 0, stream>>>(
        acat0, s0t, hA, N_NODES, HID,
        s0_b, bn_g + 0 * HID, bn_b + 0 * HID, bn_m + 0 * HID, bn_v + 0 * HID, pre_a + 0 * HID);

    // SAGE 1
    k_sage_agg_bf<<<N_NODES, 64, 0, stream>>>(hA, row_off, col, acat1);
    k_gemm<256, 8, 1><<<dim3(MB, 1), 256, 0, stream>>>(
        acat1, s1t, hB, N_NODES, HID,
        s1_b, bn_g + 1 * HID, bn_b + 1 * HID, bn_m + 1 * HID, bn_v + 1 * HID, pre_a + 1 * HID);

    // GAT 0
    k_gemm<128, 8, 0><<<dim3(MB, 4), 256, 0, stream>>>(
        hB, g0t, xw, N_NODES, HEADS * HID, nullptr, nullptr, nullptr, nullptr, nullptr, nullptr);
    k_gat_scores<<<(N_NODES * HEADS) / 4, 256, 0, stream>>>(xw, g0_as, g0_ad, es, edv);
    k_gat_agg<<<N_NODES, 256, 0, stream>>>(
        xw, es, edv, row_off, col, g0_bias,
        bn_g + 2 * HID, bn_b + 2 * HID, bn_m + 2 * HID, bn_v + 2 * HID, pre_a + 2 * HID, hA);

    // GAT 1
    k_gemm<128, 8, 0><<<dim3(MB, 4), 256, 0, stream>>>(
        hA, g1t, xw, N_NODES, HEADS * HID, nullptr, nullptr, nullptr, nullptr, nullptr, nullptr);
    k_gat_scores<<<(N_NODES * HEADS) / 4, 256, 0, stream>>>(xw, g1_as, g1_ad, es, edv);
    k_gat_agg<<<N_NODES, 256, 0, stream>>>(
        xw, es, edv, row_off, col, g1_bias,
        bn_g + 3 * HID, bn_b + 3 * HID, bn_m + 3 * HID, bn_v + 3 * HID, pre_a + 3 * HID, hB);

    // IDP MLP
    k_gemm<128, 8, 2><<<dim3(MB, 1), 256, 0, stream>>>(
        hB, idpt + 0 * 16384, hA, N_NODES, HID,
        idp_b + 0 * HID, nullptr, nullptr, nullptr, nullptr, idp_a + 0 * HID);
    k_gemm<128, 8, 2><<<dim3(MB, 1), 256, 0, stream>>>(
        hA, idpt + 1 * 16384, hB, N_NODES, HID,
        idp_b + 1 * HID, nullptr, nullptr, nullptr, nullptr, idp_a + 1 * HID);
    k_gemm<128, 8, 3><<<dim3(MB, 1), 256, 0, stream>>>(
        hB, idpt + 2 * 16384, hA, N_NODES, HID,
        idp_b + 2 * HID, nullptr, nullptr, nullptr, nullptr, nullptr);

    // global mean pool + classifier
    k_pool<<<dim3(NGRAPH, PSEG), 64, 0, stream>>>(hA, gstart, pool);
    k_cls<<<1, NGRAPH * NCLS, 0, stream>>>(pool, gstart, cls_W, cls_b, out);
}

// Round 7
// 884.524 us; speedup vs baseline: 1.1639x; 1.1639x over previous
//
#include <hip/hip_runtime.h>
#include <hip/hip_bf16.h>
#include <math.h>

// Problem constants (match reference)
#define N_NODES 50000
#define N_EDGES 800000
#define DIN     64
#define HID     128
#define HEADS   4
#define NGRAPH  64
#define NCLS    8
#define EPSB    1e-5f
#define SLOPE   0.2f
#define PSEG    16               // pooling segments per graph
#define MAXC    256              // gat_agg edge-chunk per head

#define SCB     256                            // scan block size
#define NSB     ((N_NODES + SCB - 1) / SCB)    // 196 scan blocks

#define MPAD    (N_NODES + 64)   // row padding for 64-row GEMM tiles

typedef __hip_bfloat16 bf16;
typedef __attribute__((ext_vector_type(8))) short short8;
typedef __attribute__((ext_vector_type(4))) float f32x4;

__device__ __forceinline__ float b2f(bf16 v) { return __bfloat162float(v); }
__device__ __forceinline__ bf16  f2b(float v) { return __float2bfloat16(v); }
__device__ __forceinline__ float lo_f(unsigned v) {
    unsigned u = v << 16; return __builtin_bit_cast(float, u);
}
__device__ __forceinline__ float hi_f(unsigned v) {
    unsigned u = v & 0xffff0000u; return __builtin_bit_cast(float, u);
}

// ---------------- CSR build ----------------
__global__ void k_count(const int* __restrict__ ei, int* __restrict__ deg) {
    int e = blockIdx.x * 256 + threadIdx.x;
    if (e < N_EDGES) atomicAdd(&deg[ei[N_EDGES + e]], 1);
}

// hierarchical scan: local 256-wide inclusive scan + block totals
__global__ void k_scan1(const int* __restrict__ deg, int* __restrict__ row_off,
                        int* __restrict__ bsum) {
    __shared__ int sm[SCB];
    int b = blockIdx.x, t = threadIdx.x;
    int i = b * SCB + t;
    int v = (i < N_NODES) ? deg[i] : 0;
    sm[t] = v;
    __syncthreads();
    for (int off = 1; off < SCB; off <<= 1) {
        int x = (t >= off) ? sm[t - off] : 0;
        __syncthreads();
        sm[t] += x;
        __syncthreads();
    }
    if (i < N_NODES) row_off[i + 1] = sm[t];
    if (t == SCB - 1) bsum[b] = sm[t];
}

__global__ void k_scan2(const int* __restrict__ bsum, int* __restrict__ boff) {
    __shared__ int sm[SCB];
    int t = threadIdx.x;
    int v = (t < NSB) ? bsum[t] : 0;
    sm[t] = v;
    __syncthreads();
    for (int off = 1; off < SCB; off <<= 1) {
        int x = (t >= off) ? sm[t - off] : 0;
        __syncthreads();
        sm[t] += x;
        __syncthreads();
    }
    boff[t] = sm[t] - v;   // exclusive
}

__global__ void k_scan3(int* __restrict__ row_off, const int* __restrict__ boff) {
    int i = blockIdx.x * 256 + threadIdx.x;
    if (i == 0) row_off[0] = 0;
    if (i < N_NODES) row_off[i + 1] += boff[i >> 8];
}

__global__ void k_fill(const int* __restrict__ ei, const int* __restrict__ row_off,
                       int* __restrict__ cursor, int* __restrict__ col) {
    int e = blockIdx.x * 256 + threadIdx.x;
    if (e < N_EDGES) {
        int s = ei[e], d = ei[N_EDGES + e];
        int pos = atomicAdd(&cursor[d], 1);
        col[row_off[d] + pos] = s;
    }
}

// per-graph start offsets from sorted batch
__global__ void k_bounds(const int* __restrict__ batch, int* __restrict__ gstart) {
    int i = blockIdx.x * 256 + threadIdx.x;
    if (i >= N_NODES) return;
    int b = batch[i];
    int prev = (i == 0) ? -1 : batch[i - 1];
    for (int g = prev + 1; g <= b; ++g) gstart[g] = i;
    if (i == N_NODES - 1)
        for (int g = b + 1; g <= NGRAPH; ++g) gstart[g] = N_NODES;
}

// ---------------- weight prep: convert to bf16, transposed (Bt[n][k]) ----------------
__global__ void k_prep(const float* __restrict__ s0Wl, const float* __restrict__ s0Wr,
                       const float* __restrict__ s1Wl, const float* __restrict__ s1Wr,
                       const float* __restrict__ g0W,  const float* __restrict__ g1W,
                       const float* __restrict__ idpW,
                       bf16* __restrict__ s0t, bf16* __restrict__ s1t,
                       bf16* __restrict__ g0t, bf16* __restrict__ g1t,
                       bf16* __restrict__ idpt) {
    int t = blockIdx.x * 256 + threadIdx.x;
    if (t < 16384) { int n = t >> 7, k = t & 127;
        s0t[t] = f2b(k < 64 ? s0Wl[k * 128 + n] : s0Wr[(k - 64) * 128 + n]); return; }
    t -= 16384;
    if (t < 32768) { int n = t >> 8, k = t & 255;
        s1t[t] = f2b(k < 128 ? s1Wl[k * 128 + n] : s1Wr[(k - 128) * 128 + n]); return; }
    t -= 32768;
    if (t < 65536) { int n = t >> 7, k = t & 127; g0t[t] = f2b(g0W[k * 512 + n]); return; }
    t -= 65536;
    if (t < 65536) { int n = t >> 7, k = t & 127; g1t[t] = f2b(g1W[k * 512 + n]); return; }
    t -= 65536;
    if (t < 49152) { int l = t >> 14, r = t & 16383; int n = r >> 7, k = r & 127;
        idpt[t] = f2b(idpW[l * 16384 + k * 128 + n]); }
}

// ---------------- SAGE mean-aggregate + concat self features ----------------
__global__ void k_sage_agg_f32(const float* __restrict__ xin, const int* __restrict__ row_off,
                               const int* __restrict__ col, bf16* __restrict__ acat) {
    int i = blockIdx.x;
    int c = threadIdx.x;  // 64
    int s0 = row_off[i], s1 = row_off[i + 1];
    float acc = 0.f;
    for (int j = s0; j < s1; ++j)
        acc += xin[(size_t)col[j] * DIN + c];
    acat[(size_t)i * (2 * DIN) + c]       = f2b(acc / fmaxf((float)(s1 - s0), 1.0f));
    acat[(size_t)i * (2 * DIN) + DIN + c] = f2b(xin[(size_t)i * DIN + c]);
}

__global__ void k_sage_agg_bf(const bf16* __restrict__ xin, const int* __restrict__ row_off,
                              const int* __restrict__ col, bf16* __restrict__ acat) {
    int i = blockIdx.x;
    int c = threadIdx.x;  // 64 lanes, channels 2c,2c+1
    int s0 = row_off[i], s1 = row_off[i + 1];
    const unsigned* xb = (const unsigned*)xin;
    float a0 = 0.f, a1 = 0.f;
    for (int j = s0; j < s1; ++j) {
        unsigned v = xb[(size_t)col[j] * (HID / 2) + c];
        a0 += lo_f(v); a1 += hi_f(v);
    }
    float inv = 1.0f / fmaxf((float)(s1 - s0), 1.0f);
    acat[(size_t)i * (2 * HID) + 2 * c]     = f2b(a0 * inv);
    acat[(size_t)i * (2 * HID) + 2 * c + 1] = f2b(a1 * inv);
    ((unsigned*)acat)[(size_t)i * HID + (HID / 2) + c] = xb[(size_t)i * (HID / 2) + c];
}

// ---------------- MFMA GEMM: C[M x Nc] = A[M x K] @ Bt^T, fused epilogue ----------------
// EPI: 0=none  1=bias+BN+PReLU  2=bias+PReLU  3=bias
template <int K, int NT, int EPI>
__global__ __launch_bounds__(256) void k_gemm(
        const bf16* __restrict__ A, const bf16* __restrict__ Bt, bf16* __restrict__ C,
        int M, int Nc,
        const float* __restrict__ bias, const float* __restrict__ bng,
        const float* __restrict__ bnb,  const float* __restrict__ bnm,
        const float* __restrict__ bnv,  const float* __restrict__ pa) {
    int wave = threadIdx.x >> 6, lane = threadIdx.x & 63;
    int ln = lane & 15, q = lane >> 4;
    int m0 = blockIdx.x * 64 + wave * 16;
    int n0 = blockIdx.y * (NT * 16);
    const bf16* arow = A + (size_t)(m0 + ln) * K + q * 8;

    f32x4 acc[NT];
#pragma unroll
    for (int t = 0; t < NT; ++t) acc[t] = (f32x4){0.f, 0.f, 0.f, 0.f};

#pragma unroll
    for (int k = 0; k < K; k += 32) {
        short8 a = *(const short8*)(const void*)(arow + k);
#pragma unroll
        for (int t = 0; t < NT; ++t) {
            short8 b = *(const short8*)(const void*)(Bt + (size_t)(n0 + t * 16 + ln) * K + k + q * 8);
            acc[t] = __builtin_amdgcn_mfma_f32_16x16x32_bf16(a, b, acc[t], 0, 0, 0);
        }
    }

#pragma unroll
    for (int t = 0; t < NT; ++t) {
        int cidx = n0 + t * 16 + ln;
        float bi = 0.f, g = 1.f, bb = 0.f, mm = 0.f, iv = 1.f, al = 1.f;
        if (EPI >= 1) bi = bias[cidx];
        if (EPI == 1) { g = bng[cidx]; bb = bnb[cidx]; mm = bnm[cidx]; iv = rsqrtf(bnv[cidx] + EPSB); }
        if (EPI == 1 || EPI == 2) al = pa[cidx];
#pragma unroll
        for (int r = 0; r < 4; ++r) {
            int mr = m0 + q * 4 + r;
            if (mr < M) {
                float v = acc[t][r] + bi;
                if (EPI == 1) v = (v - mm) * iv * g + bb;
                if (EPI == 1 || EPI == 2) v = v >= 0.f ? v : al * v;
                C[(size_t)mr * Nc + cidx] = f2b(v);
            }
        }
    }
}

// ---------------- GAT ----------------
__global__ void k_gat_scores(const bf16* __restrict__ xw, const float* __restrict__ as,
                             const float* __restrict__ ad,
                             float* __restrict__ es, float* __restrict__ ed) {
    int wid = (blockIdx.x * 256 + threadIdx.x) >> 6;
    int lane = threadIdx.x & 63;
    if (wid >= N_NODES * HEADS) return;
    int i = wid / HEADS, h = wid % HEADS;
    const bf16* row = xw + (size_t)i * (HEADS * HID) + h * HID;
    float v0 = b2f(row[lane]), v1 = b2f(row[lane + 64]);
    float s1 = v0 * as[h * HID + lane] + v1 * as[h * HID + lane + 64];
    float s2 = v0 * ad[h * HID + lane] + v1 * ad[h * HID + lane + 64];
    for (int off = 32; off; off >>= 1) {
        s1 += __shfl_down(s1, off, 64);
        s2 += __shfl_down(s2, off, 64);
    }
    if (lane == 0) { es[i * HEADS + h] = s1; ed[i * HEADS + h] = s2; }
}

// Per-node GAT aggregation: wave w = head w.
// No max-subtraction (softmax shift-invariant; scores bounded, no overflow).
// Phase A: lane-parallel expf scores into per-wave LDS (once per edge-head).
// Phase B: serial over edges, full wave on ONE row per iteration — 4 B/lane
//          coalesced 256 B gather (uint2 split-row variant regressed: R5→R6).
__global__ __launch_bounds__(256) void k_gat_agg(
        const bf16* __restrict__ xw, const float* __restrict__ es,
        const float* __restrict__ ed, const int* __restrict__ row_off,
        const int* __restrict__ col, const float* __restrict__ bias,
        const float* __restrict__ bng, const float* __restrict__ bnb,
        const float* __restrict__ bnm, const float* __restrict__ bnv,
        const float* __restrict__ pa,
        bf16* __restrict__ out) {
    __shared__ float sEx[HEADS][MAXC];
    __shared__ int   sCol[HEADS][MAXC];
    __shared__ float sO[HEADS][HID];
    int i = blockIdx.x;
    int w = threadIdx.x >> 6;   // head
    int lane = threadIdx.x & 63;
    int s0 = row_off[i], s1 = row_off[i + 1];
    float edi = ed[i * HEADS + w];
    float esi = es[i * HEADS + w];
    const unsigned* xwb = (const unsigned*)xw;   // row stride 256 uints

    float den = 0.f, a0 = 0.f, a1 = 0.f;
    {   // self loop — den counted exactly once (lane 0)
        float e = esi + edi;
        e = e >= 0.f ? e : SLOPE * e;
        float ex = expf(e);
        if (lane == 0) den = ex;
        unsigned v = xwb[(size_t)i * 256 + w * 64 + lane];
        a0 += ex * lo_f(v);
        a1 += ex * hi_f(v);
    }
    for (int c0 = s0; c0 < s1; c0 += MAXC) {
        int cnt = min(MAXC, s1 - c0);
        // phase A: per-edge exp scores (one lane per edge)
        for (int l = lane; l < cnt; l += 64) {
            int s = col[c0 + l];
            float e = es[s * HEADS + w] + edi;
            e = e >= 0.f ? e : SLOPE * e;
            float ex = expf(e);
            den += ex;
            sEx[w][l]  = ex;
            sCol[w][l] = s;
        }
        // same-wave LDS write->read: program order, no block barrier needed
        // phase B: serial over edges, lanes over features (one row per iter)
        for (int e = 0; e < cnt; ++e) {
            float ex = sEx[w][e];
            int s = sCol[w][e];
            unsigned v = xwb[(size_t)s * 256 + w * 64 + lane];
            a0 += ex * lo_f(v);
            a1 += ex * hi_f(v);
        }
    }
    for (int off = 32; off; off >>= 1) den += __shfl_down(den, off, 64);
    den = __shfl(den, 0, 64);

    float inv = 1.0f / den;
    sO[w][2 * lane]     = a0 * inv;
    sO[w][2 * lane + 1] = a1 * inv;
    __syncthreads();
    int j = threadIdx.x;
    if (j < HID) {
        float v = 0.25f * (sO[0][j] + sO[1][j] + sO[2][j] + sO[3][j]) + bias[j];
        float g = bng[j], bb = bnb[j], mm = bnm[j], vv = bnv[j];
        v = (v - mm) * rsqrtf(vv + EPSB) * g + bb;
        float a = pa[j];
        out[(size_t)i * HID + j] = f2b(v >= 0.f ? v : a * v);
    }
}

// ---------------- pool / classifier ----------------
__global__ void k_pool(const bf16* __restrict__ h, const int* __restrict__ gstart,
                       float* __restrict__ pool) {
    int g = blockIdx.x, s = blockIdx.y;
    int c = threadIdx.x;   // 64 lanes, channels 2c,2c+1
    int b0 = gstart[g], b1 = gstart[g + 1];
    int len = b1 - b0;
    if (len <= 0) return;
    int per = (len + PSEG - 1) / PSEG;
    int r0 = b0 + s * per;
    int r1 = min(r0 + per, b1);
    if (r0 >= r1) return;
    const unsigned* hb = (const unsigned*)h;
    float a0 = 0.f, a1 = 0.f;
    for (int i = r0; i < r1; ++i) {
        unsigned v = hb[(size_t)i * (HID / 2) + c];
        a0 += lo_f(v); a1 += hi_f(v);
    }
    atomicAdd(&pool[g * HID + 2 * c], a0);
    atomicAdd(&pool[g * HID + 2 * c + 1], a1);
}

__global__ void k_cls(const float* __restrict__ pool, const int* __restrict__ gstart,
                      const float* __restrict__ W, const float* __restrict__ b,
                      float* __restrict__ out) {
    int t = threadIdx.x;            // 512 = 64*8
    int g = t / NCLS, n = t % NCLS;
    float ic = 1.0f / fmaxf((float)(gstart[g + 1] - gstart[g]), 1.0f);
    float acc = b[n];
    for (int k = 0; k < HID; ++k)
        acc += pool[g * HID + k] * ic * W[k * NCLS + n];
    out[g * NCLS + n] = acc;
}

// ---------------- launch ----------------
extern "C" void kernel_launch(void* const* d_in, const int* in_sizes, int n_in,
                              void* d_out, int out_size, void* d_ws, size_t ws_size,
                              hipStream_t stream) {
    const float* x      = (const float*)d_in[0];
    const int*   ei     = (const int*)d_in[1];
    const int*   batch  = (const int*)d_in[2];
    const float* s0_Wl  = (const float*)d_in[3];
    const float* s0_Wr  = (const float*)d_in[4];
    const float* s0_b   = (const float*)d_in[5];
    const float* s1_Wl  = (const float*)d_in[6];
    const float* s1_Wr  = (const float*)d_in[7];
    const float* s1_b   = (const float*)d_in[8];
    const float* bn_g   = (const float*)d_in[9];
    const float* bn_b   = (const float*)d_in[10];
    const float* bn_m   = (const float*)d_in[11];
    const float* bn_v   = (const float*)d_in[12];
    const float* pre_a  = (const float*)d_in[13];
    const float* g0_W   = (const float*)d_in[14];
    const float* g0_as  = (const float*)d_in[15];
    const float* g0_ad  = (const float*)d_in[16];
    const float* g0_bias= (const float*)d_in[17];
    const float* g1_W   = (const float*)d_in[18];
    const float* g1_as  = (const float*)d_in[19];
    const float* g1_ad  = (const float*)d_in[20];
    const float* g1_bias= (const float*)d_in[21];
    const float* idp_W  = (const float*)d_in[22];
    const float* idp_b  = (const float*)d_in[23];
    const float* idp_a  = (const float*)d_in[24];
    const float* cls_W  = (const float*)d_in[25];
    const float* cls_b  = (const float*)d_in[26];
    float* out = (float*)d_out;

    // workspace carve (256B aligned)
    char* p = (char*)d_ws;
    auto alloc = [&](size_t bytes) -> void* {
        void* r = (void*)p;
        p += (bytes + 255) & ~(size_t)255;
        return r;
    };
    int*   deg     = (int*)alloc((size_t)N_NODES * 4);
    int*   cursor  = (int*)alloc((size_t)N_NODES * 4);
    int*   row_off = (int*)alloc((size_t)(N_NODES + 1) * 4);
    int*   col     = (int*)alloc((size_t)N_EDGES * 4);
    int*   gstart  = (int*)alloc((size_t)(NGRAPH + 1) * 4);
    int*   bsum    = (int*)alloc((size_t)SCB * 4);
    int*   boff    = (int*)alloc((size_t)SCB * 4);
    float* es      = (float*)alloc((size_t)N_NODES * HEADS * 4);
    float* edv     = (float*)alloc((size_t)N_NODES * HEADS * 4);
    float* pool    = (float*)alloc((size_t)NGRAPH * HID * 4);
    bf16*  hA      = (bf16*)alloc((size_t)MPAD * HID * 2);
    bf16*  hB      = (bf16*)alloc((size_t)MPAD * HID * 2);
    // union: acat0 (MPAD*128 bf16), acat1 (MPAD*256 bf16), xw (MPAD*512 bf16)
    bf16*  u       = (bf16*)alloc((size_t)MPAD * (HEADS * HID) * 2);
    bf16*  acat0   = u;
    bf16*  acat1   = u;
    bf16*  xw      = u;
    // bf16 transposed weights
    bf16*  s0t     = (bf16*)alloc((size_t)128 * 128 * 2);
    bf16*  s1t     = (bf16*)alloc((size_t)128 * 256 * 2);
    bf16*  g0t     = (bf16*)alloc((size_t)512 * 128 * 2);
    bf16*  g1t     = (bf16*)alloc((size_t)512 * 128 * 2);
    bf16*  idpt    = (bf16*)alloc((size_t)3 * 128 * 128 * 2);

    hipMemsetAsync(deg, 0, (size_t)N_NODES * 4, stream);
    hipMemsetAsync(cursor, 0, (size_t)N_NODES * 4, stream);
    hipMemsetAsync(pool, 0, (size_t)NGRAPH * HID * 4, stream);

    // weight prep + CSR build + graph bounds
    k_prep<<<(229376 + 255) / 256, 256, 0, stream>>>(s0_Wl, s0_Wr, s1_Wl, s1_Wr,
                                                     g0_W, g1_W, idp_W,
                                                     s0t, s1t, g0t, g1t, idpt);
    k_count<<<(N_EDGES + 255) / 256, 256, 0, stream>>>(ei, deg);
    k_scan1<<<NSB, SCB, 0, stream>>>(deg, row_off, bsum);
    k_scan2<<<1, SCB, 0, stream>>>(bsum, boff);
    k_scan3<<<(N_NODES + 255) / 256, 256, 0, stream>>>(row_off, boff);
    k_fill<<<(N_EDGES + 255) / 256, 256, 0, stream>>>(ei, row_off, cursor, col);
    k_bounds<<<(N_NODES + 255) / 256, 256, 0, stream>>>(batch, gstart);

    const int MB = (N_NODES + 63) / 64;   // 782 row-blocks

    // SAGE 0
    k_sage_agg_f32<<<N_NODES, DIN, 0, stream>>>(x, row_off, col, acat0);
    k_gemm<128, 8, 1><<<dim3(MB, 1), 256, 0, stream>>>(
        acat0, s0t, hA, N_NODES, HID,
        s0_b, bn_g + 0 * HID, bn_b + 0 * HID, bn_m + 0 * HID, bn_v + 0 * HID, pre_a + 0 * HID);

    // SAGE 1
    k_sage_agg_bf<<<N_NODES, 64, 0, stream>>>(hA, row_off, col, acat1);
    k_gemm<256, 8, 1><<<dim3(MB, 1), 256, 0, stream>>>(
        acat1, s1t, hB, N_NODES, HID,
        s1_b, bn_g + 1 * HID, bn_b + 1 * HID, bn_m + 1 * HID, bn_v + 1 * HID, pre_a + 1 * HID);

    // GAT 0
    k_gemm<128, 8, 0><<<dim3(MB, 4), 256, 0, stream>>>(
        hB, g0t, xw, N_NODES, HEADS * HID, nullptr, nullptr, nullptr, nullptr, nullptr, nullptr);
    k_gat_scores<<<(N_NODES * HEADS) / 4, 256, 0, stream>>>(xw, g0_as, g0_ad, es, edv);
    k_gat_agg<<<N_NODES, 256, 0, stream>>>(
        xw, es, edv, row_off, col, g0_bias,
        bn_g + 2 * HID, bn_b + 2 * HID, bn_m + 2 * HID, bn_v + 2 * HID, pre_a + 2 * HID, hA);

    // GAT 1
    k_gemm<128, 8, 0><<<dim3(MB, 4), 256, 0, stream>>>(
        hA, g1t, xw, N_NODES, HEADS * HID, nullptr, nullptr, nullptr, nullptr, nullptr, nullptr);
    k_gat_scores<<<(N_NODES * HEADS) / 4, 256, 0, stream>>>(xw, g1_as, g1_ad, es, edv);
    k_gat_agg<<<N_NODES, 256, 0, stream>>>(
        xw, es, edv, row_off, col, g1_bias,
        bn_g + 3 * HID, bn_b + 3 * HID, bn_m + 3 * HID, bn_v + 3 * HID, pre_a + 3 * HID, hB);

    // IDP MLP
    k_gemm<128, 8, 2><<<dim3(MB, 1), 256, 0, stream>>>(
        hB, idpt + 0 * 16384, hA, N_NODES, HID,
        idp_b + 0 * HID, nullptr, nullptr, nullptr, nullptr, idp_a + 0 * HID);
    k_gemm<128, 8, 2><<<dim3(MB, 1), 256, 0, stream>>>(
        hA, idpt + 1 * 16384, hB, N_NODES, HID,
        idp_b + 1 * HID, nullptr, nullptr, nullptr, nullptr, idp_a + 1 * HID);
    k_gemm<128, 8, 3><<<dim3(MB, 1), 256, 0, stream>>>(
        hB, idpt + 2 * 16384, hA, N_NODES, HID,
        idp_b + 2 * HID, nullptr, nullptr, nullptr, nullptr, nullptr);

    // global mean pool + classifier
    k_pool<<<dim3(NGRAPH, PSEG), 64, 0, stream>>>(hA, gstart, pool);
    k_cls<<<1, NGRAPH * NCLS, 0, stream>>>(pool, gstart, cls_W, cls_b, out);
}

// Round 8
// 871.914 us; speedup vs baseline: 1.1808x; 1.0145x over previous
//
#include <hip/hip_runtime.h>
#include <hip/hip_bf16.h>
#include <math.h>

// Problem constants (match reference)
#define N_NODES 50000
#define N_EDGES 800000
#define DIN     64
#define HID     128
#define HEADS   4
#define NGRAPH  64
#define NCLS    8
#define EPSB    1e-5f
#define SLOPE   0.2f
#define PSEG    16               // pooling segments per graph
#define MAXC4   64               // gat_agg edge-chunk (one lane per edge)

#define SCB     256                            // scan block size
#define NSB     ((N_NODES + SCB - 1) / SCB)    // 196 scan blocks

#define MPAD    (N_NODES + 64)   // row padding for 64-row GEMM tiles

typedef __hip_bfloat16 bf16;
typedef __attribute__((ext_vector_type(8))) short short8;
typedef __attribute__((ext_vector_type(4))) float f32x4;

__device__ __forceinline__ float b2f(bf16 v) { return __bfloat162float(v); }
__device__ __forceinline__ bf16  f2b(float v) { return __float2bfloat16(v); }
__device__ __forceinline__ float lo_f(unsigned v) {
    unsigned u = v << 16; return __builtin_bit_cast(float, u);
}
__device__ __forceinline__ float hi_f(unsigned v) {
    unsigned u = v & 0xffff0000u; return __builtin_bit_cast(float, u);
}
__device__ __forceinline__ unsigned packbf(float lo, float hi) {
    unsigned l = (unsigned)__builtin_bit_cast(unsigned short, __float2bfloat16(lo));
    unsigned h = (unsigned)__builtin_bit_cast(unsigned short, __float2bfloat16(hi));
    return (h << 16) | l;
}

// ---------------- CSR build ----------------
__global__ void k_count(const int* __restrict__ ei, int* __restrict__ deg) {
    int e = blockIdx.x * 256 + threadIdx.x;
    if (e < N_EDGES) atomicAdd(&deg[ei[N_EDGES + e]], 1);
}

// hierarchical scan: local 256-wide inclusive scan + block totals
__global__ void k_scan1(const int* __restrict__ deg, int* __restrict__ row_off,
                        int* __restrict__ bsum) {
    __shared__ int sm[SCB];
    int b = blockIdx.x, t = threadIdx.x;
    int i = b * SCB + t;
    int v = (i < N_NODES) ? deg[i] : 0;
    sm[t] = v;
    __syncthreads();
    for (int off = 1; off < SCB; off <<= 1) {
        int x = (t >= off) ? sm[t - off] : 0;
        __syncthreads();
        sm[t] += x;
        __syncthreads();
    }
    if (i < N_NODES) row_off[i + 1] = sm[t];
    if (t == SCB - 1) bsum[b] = sm[t];
}

__global__ void k_scan2(const int* __restrict__ bsum, int* __restrict__ boff) {
    __shared__ int sm[SCB];
    int t = threadIdx.x;
    int v = (t < NSB) ? bsum[t] : 0;
    sm[t] = v;
    __syncthreads();
    for (int off = 1; off < SCB; off <<= 1) {
        int x = (t >= off) ? sm[t - off] : 0;
        __syncthreads();
        sm[t] += x;
        __syncthreads();
    }
    boff[t] = sm[t] - v;   // exclusive
}

__global__ void k_scan3(int* __restrict__ row_off, const int* __restrict__ boff) {
    int i = blockIdx.x * 256 + threadIdx.x;
    if (i == 0) row_off[0] = 0;
    if (i < N_NODES) row_off[i + 1] += boff[i >> 8];
}

__global__ void k_fill(const int* __restrict__ ei, const int* __restrict__ row_off,
                       int* __restrict__ cursor, int* __restrict__ col) {
    int e = blockIdx.x * 256 + threadIdx.x;
    if (e < N_EDGES) {
        int s = ei[e], d = ei[N_EDGES + e];
        int pos = atomicAdd(&cursor[d], 1);
        col[row_off[d] + pos] = s;
    }
}

// per-graph start offsets from sorted batch
__global__ void k_bounds(const int* __restrict__ batch, int* __restrict__ gstart) {
    int i = blockIdx.x * 256 + threadIdx.x;
    if (i >= N_NODES) return;
    int b = batch[i];
    int prev = (i == 0) ? -1 : batch[i - 1];
    for (int g = prev + 1; g <= b; ++g) gstart[g] = i;
    if (i == N_NODES - 1)
        for (int g = b + 1; g <= NGRAPH; ++g) gstart[g] = N_NODES;
}

// ---------------- weight prep: convert to bf16, transposed (Bt[n][k]) ----------------
__global__ void k_prep(const float* __restrict__ s0Wl, const float* __restrict__ s0Wr,
                       const float* __restrict__ s1Wl, const float* __restrict__ s1Wr,
                       const float* __restrict__ g0W,  const float* __restrict__ g1W,
                       const float* __restrict__ idpW,
                       bf16* __restrict__ s0t, bf16* __restrict__ s1t,
                       bf16* __restrict__ g0t, bf16* __restrict__ g1t,
                       bf16* __restrict__ idpt) {
    int t = blockIdx.x * 256 + threadIdx.x;
    if (t < 16384) { int n = t >> 7, k = t & 127;
        s0t[t] = f2b(k < 64 ? s0Wl[k * 128 + n] : s0Wr[(k - 64) * 128 + n]); return; }
    t -= 16384;
    if (t < 32768) { int n = t >> 8, k = t & 255;
        s1t[t] = f2b(k < 128 ? s1Wl[k * 128 + n] : s1Wr[(k - 128) * 128 + n]); return; }
    t -= 32768;
    if (t < 65536) { int n = t >> 7, k = t & 127; g0t[t] = f2b(g0W[k * 512 + n]); return; }
    t -= 65536;
    if (t < 65536) { int n = t >> 7, k = t & 127; g1t[t] = f2b(g1W[k * 512 + n]); return; }
    t -= 65536;
    if (t < 49152) { int l = t >> 14, r = t & 16383; int n = r >> 7, k = r & 127;
        idpt[t] = f2b(idpW[l * 16384 + k * 128 + n]); }
}

// ---------------- SAGE mean-aggregate + concat self features ----------------
__global__ void k_sage_agg_f32(const float* __restrict__ xin, const int* __restrict__ row_off,
                               const int* __restrict__ col, bf16* __restrict__ acat) {
    int i = blockIdx.x;
    int c = threadIdx.x;  // 64
    int s0 = row_off[i], s1 = row_off[i + 1];
    float acc = 0.f;
    for (int j = s0; j < s1; ++j)
        acc += xin[(size_t)col[j] * DIN + c];
    acat[(size_t)i * (2 * DIN) + c]       = f2b(acc / fmaxf((float)(s1 - s0), 1.0f));
    acat[(size_t)i * (2 * DIN) + DIN + c] = f2b(xin[(size_t)i * DIN + c]);
}

__global__ void k_sage_agg_bf(const bf16* __restrict__ xin, const int* __restrict__ row_off,
                              const int* __restrict__ col, bf16* __restrict__ acat) {
    int i = blockIdx.x;
    int c = threadIdx.x;  // 64 lanes, channels 2c,2c+1
    int s0 = row_off[i], s1 = row_off[i + 1];
    const unsigned* xb = (const unsigned*)xin;
    float a0 = 0.f, a1 = 0.f;
    for (int j = s0; j < s1; ++j) {
        unsigned v = xb[(size_t)col[j] * (HID / 2) + c];
        a0 += lo_f(v); a1 += hi_f(v);
    }
    float inv = 1.0f / fmaxf((float)(s1 - s0), 1.0f);
    acat[(size_t)i * (2 * HID) + 2 * c]     = f2b(a0 * inv);
    acat[(size_t)i * (2 * HID) + 2 * c + 1] = f2b(a1 * inv);
    ((unsigned*)acat)[(size_t)i * HID + (HID / 2) + c] = xb[(size_t)i * (HID / 2) + c];
}

// ---------------- MFMA GEMM: C[M x Nc] = A[M x K] @ Bt^T, fused epilogue ----------------
// EPI: 0=none  1=bias+BN+PReLU  2=bias+PReLU  3=bias
template <int K, int NT, int EPI>
__global__ __launch_bounds__(256) void k_gemm(
        const bf16* __restrict__ A, const bf16* __restrict__ Bt, bf16* __restrict__ C,
        int M, int Nc,
        const float* __restrict__ bias, const float* __restrict__ bng,
        const float* __restrict__ bnb,  const float* __restrict__ bnm,
        const float* __restrict__ bnv,  const float* __restrict__ pa) {
    int wave = threadIdx.x >> 6, lane = threadIdx.x & 63;
    int ln = lane & 15, q = lane >> 4;
    int m0 = blockIdx.x * 64 + wave * 16;
    int n0 = blockIdx.y * (NT * 16);
    const bf16* arow = A + (size_t)(m0 + ln) * K + q * 8;

    f32x4 acc[NT];
#pragma unroll
    for (int t = 0; t < NT; ++t) acc[t] = (f32x4){0.f, 0.f, 0.f, 0.f};

#pragma unroll
    for (int k = 0; k < K; k += 32) {
        short8 a = *(const short8*)(const void*)(arow + k);
#pragma unroll
        for (int t = 0; t < NT; ++t) {
            short8 b = *(const short8*)(const void*)(Bt + (size_t)(n0 + t * 16 + ln) * K + k + q * 8);
            acc[t] = __builtin_amdgcn_mfma_f32_16x16x32_bf16(a, b, acc[t], 0, 0, 0);
        }
    }

#pragma unroll
    for (int t = 0; t < NT; ++t) {
        int cidx = n0 + t * 16 + ln;
        float bi = 0.f, g = 1.f, bb = 0.f, mm = 0.f, iv = 1.f, al = 1.f;
        if (EPI >= 1) bi = bias[cidx];
        if (EPI == 1) { g = bng[cidx]; bb = bnb[cidx]; mm = bnm[cidx]; iv = rsqrtf(bnv[cidx] + EPSB); }
        if (EPI == 1 || EPI == 2) al = pa[cidx];
#pragma unroll
        for (int r = 0; r < 4; ++r) {
            int mr = m0 + q * 4 + r;
            if (mr < M) {
                float v = acc[t][r] + bi;
                if (EPI == 1) v = (v - mm) * iv * g + bb;
                if (EPI == 1 || EPI == 2) v = v >= 0.f ? v : al * v;
                C[(size_t)mr * Nc + cidx] = f2b(v);
            }
        }
    }
}

// ---------------- GAT ----------------
__global__ void k_gat_scores(const bf16* __restrict__ xw, const float* __restrict__ as,
                             const float* __restrict__ ad,
                             float* __restrict__ es, float* __restrict__ ed) {
    int wid = (blockIdx.x * 256 + threadIdx.x) >> 6;
    int lane = threadIdx.x & 63;
    if (wid >= N_NODES * HEADS) return;
    int i = wid >> 2, h = wid & 3;
    const unsigned* row = (const unsigned*)(xw + (size_t)i * (HEADS * HID) + h * HID);
    unsigned v = row[lane];
    float2 a2 = ((const float2*)(as + h * HID))[lane];
    float2 d2 = ((const float2*)(ad + h * HID))[lane];
    float s1 = lo_f(v) * a2.x + hi_f(v) * a2.y;
    float s2 = lo_f(v) * d2.x + hi_f(v) * d2.y;
    for (int off = 32; off; off >>= 1) {
        s1 += __shfl_down(s1, off, 64);
        s2 += __shfl_down(s2, off, 64);
    }
    if (lane == 0) { es[i * HEADS + h] = s1; ed[i * HEADS + h] = s2; }
}

// Per-node GAT aggregation: ONE wave per node, all 4 heads.
// No max-subtraction (softmax shift-invariant; scores bounded, no overflow).
// Phase A: lane j handles edge j — float4 es gather, 4 expf, den partials,
//          ex4+col into per-wave LDS.
// Phase B: per edge the whole wave reads the full 1 KB row as uint4
//          (16 B/lane dwordx4) — lane l covers channels 8l..8l+7 (head l>>4).
// Epilogue: head-mean via shfl_xor(16,32), bias+BN+PReLU, packed uint4 stores.
__global__ __launch_bounds__(256) void k_gat_agg(
        const bf16* __restrict__ xw, const float* __restrict__ es,
        const float* __restrict__ ed, const int* __restrict__ row_off,
        const int* __restrict__ col, const float* __restrict__ bias,
        const float* __restrict__ bng, const float* __restrict__ bnb,
        const float* __restrict__ bnm, const float* __restrict__ bnv,
        const float* __restrict__ pa,
        bf16* __restrict__ out) {
    __shared__ __align__(16) float sEx[4][MAXC4][HEADS];
    __shared__ int sCol[4][MAXC4];
    int w = threadIdx.x >> 6;
    int lane = threadIdx.x & 63;
    int i = blockIdx.x * 4 + w;          // grid = N/4 exactly
    int h = lane >> 4;
    const uint4*  xw4 = (const uint4*)xw;     // row = 64 uint4 (1 KB)
    const float4* es4 = (const float4*)es;
    float4 edi = ((const float4*)ed)[i];

    int s0 = row_off[i], s1 = row_off[i + 1];
    float den0 = 0.f, den1 = 0.f, den2 = 0.f, den3 = 0.f;
    float a[8];
#pragma unroll
    for (int j = 0; j < 8; ++j) a[j] = 0.f;

    {   // self loop
        float4 ev = es4[i];
        float e0 = ev.x + edi.x; e0 = e0 >= 0.f ? e0 : SLOPE * e0; float x0 = expf(e0);
        float e1 = ev.y + edi.y; e1 = e1 >= 0.f ? e1 : SLOPE * e1; float x1 = expf(e1);
        float e2 = ev.z + edi.z; e2 = e2 >= 0.f ? e2 : SLOPE * e2; float x2 = expf(e2);
        float e3 = ev.w + edi.w; e3 = e3 >= 0.f ? e3 : SLOPE * e3; float x3 = expf(e3);
        if (lane == 0) { den0 = x0; den1 = x1; den2 = x2; den3 = x3; }
        float exh = h == 0 ? x0 : h == 1 ? x1 : h == 2 ? x2 : x3;
        uint4 v = xw4[(size_t)i * 64 + lane];
        a[0] += exh * lo_f(v.x); a[1] += exh * hi_f(v.x);
        a[2] += exh * lo_f(v.y); a[3] += exh * hi_f(v.y);
        a[4] += exh * lo_f(v.z); a[5] += exh * hi_f(v.z);
        a[6] += exh * lo_f(v.w); a[7] += exh * hi_f(v.w);
    }
    for (int c0 = s0; c0 < s1; c0 += MAXC4) {
        int cnt = min(MAXC4, s1 - c0);
        if (lane < cnt) {
            int s = col[c0 + lane];
            float4 ev = es4[s];
            float e0 = ev.x + edi.x; e0 = e0 >= 0.f ? e0 : SLOPE * e0; float x0 = expf(e0);
            float e1 = ev.y + edi.y; e1 = e1 >= 0.f ? e1 : SLOPE * e1; float x1 = expf(e1);
            float e2 = ev.z + edi.z; e2 = e2 >= 0.f ? e2 : SLOPE * e2; float x2 = expf(e2);
            float e3 = ev.w + edi.w; e3 = e3 >= 0.f ? e3 : SLOPE * e3; float x3 = expf(e3);
            den0 += x0; den1 += x1; den2 += x2; den3 += x3;
            sCol[w][lane] = s;
            f32x4 xv = {x0, x1, x2, x3};
            *(f32x4*)(&sEx[w][lane][0]) = xv;
        }
        // same-wave LDS write->read: program order, no block barrier needed
        for (int e = 0; e < cnt; ++e) {
            float ex = sEx[w][e][h];
            int s = sCol[w][e];
            uint4 v = xw4[(size_t)s * 64 + lane];
            a[0] += ex * lo_f(v.x); a[1] += ex * hi_f(v.x);
            a[2] += ex * lo_f(v.y); a[3] += ex * hi_f(v.y);
            a[4] += ex * lo_f(v.z); a[5] += ex * hi_f(v.z);
            a[6] += ex * lo_f(v.w); a[7] += ex * hi_f(v.w);
        }
    }
    // den: butterfly so every lane holds all 4 totals
    for (int off = 1; off < 64; off <<= 1) {
        den0 += __shfl_xor(den0, off, 64);
        den1 += __shfl_xor(den1, off, 64);
        den2 += __shfl_xor(den2, off, 64);
        den3 += __shfl_xor(den3, off, 64);
    }
    float den = h == 0 ? den0 : h == 1 ? den1 : h == 2 ? den2 : den3;
    float inv = 1.0f / den;
    float m[8];
#pragma unroll
    for (int j = 0; j < 8; ++j) m[j] = a[j] * inv;
    // head mean: lanes l, l^16, l^32, l^48 hold heads 0..3 of identical channels
#pragma unroll
    for (int j = 0; j < 8; ++j) {
        m[j] += __shfl_xor(m[j], 16, 64);
        m[j] += __shfl_xor(m[j], 32, 64);
    }
    if (lane < 16) {
        int cb = lane * 8;
        float r[8];
#pragma unroll
        for (int j = 0; j < 8; ++j) {
            int c = cb + j;
            float v = 0.25f * m[j] + bias[c];
            v = (v - bnm[c]) * rsqrtf(bnv[c] + EPSB) * bng[c] + bnb[c];
            float al = pa[c];
            r[j] = v >= 0.f ? v : al * v;
        }
        uint4 o;
        o.x = packbf(r[0], r[1]); o.y = packbf(r[2], r[3]);
        o.z = packbf(r[4], r[5]); o.w = packbf(r[6], r[7]);
        ((uint4*)out)[(size_t)i * 16 + lane] = o;
    }
}

// ---------------- pool / classifier ----------------
__global__ void k_pool(const bf16* __restrict__ h, const int* __restrict__ gstart,
                       float* __restrict__ pool) {
    int g = blockIdx.x, s = blockIdx.y;
    int c = threadIdx.x;   // 64 lanes, channels 2c,2c+1
    int b0 = gstart[g], b1 = gstart[g + 1];
    int len = b1 - b0;
    if (len <= 0) return;
    int per = (len + PSEG - 1) / PSEG;
    int r0 = b0 + s * per;
    int r1 = min(r0 + per, b1);
    if (r0 >= r1) return;
    const unsigned* hb = (const unsigned*)h;
    float a0 = 0.f, a1 = 0.f;
    for (int i = r0; i < r1; ++i) {
        unsigned v = hb[(size_t)i * (HID / 2) + c];
        a0 += lo_f(v); a1 += hi_f(v);
    }
    atomicAdd(&pool[g * HID + 2 * c], a0);
    atomicAdd(&pool[g * HID + 2 * c + 1], a1);
}

__global__ void k_cls(const float* __restrict__ pool, const int* __restrict__ gstart,
                      const float* __restrict__ W, const float* __restrict__ b,
                      float* __restrict__ out) {
    int t = threadIdx.x;            // 512 = 64*8
    int g = t / NCLS, n = t % NCLS;
    float ic = 1.0f / fmaxf((float)(gstart[g + 1] - gstart[g]), 1.0f);
    float acc = b[n];
    for (int k = 0; k < HID; ++k)
        acc += pool[g * HID + k] * ic * W[k * NCLS + n];
    out[g * NCLS + n] = acc;
}

// ---------------- launch ----------------
extern "C" void kernel_launch(void* const* d_in, const int* in_sizes, int n_in,
                              void* d_out, int out_size, void* d_ws, size_t ws_size,
                              hipStream_t stream) {
    const float* x      = (const float*)d_in[0];
    const int*   ei     = (const int*)d_in[1];
    const int*   batch  = (const int*)d_in[2];
    const float* s0_Wl  = (const float*)d_in[3];
    const float* s0_Wr  = (const float*)d_in[4];
    const float* s0_b   = (const float*)d_in[5];
    const float* s1_Wl  = (const float*)d_in[6];
    const float* s1_Wr  = (const float*)d_in[7];
    const float* s1_b   = (const float*)d_in[8];
    const float* bn_g   = (const float*)d_in[9];
    const float* bn_b   = (const float*)d_in[10];
    const float* bn_m   = (const float*)d_in[11];
    const float* bn_v   = (const float*)d_in[12];
    const float* pre_a  = (const float*)d_in[13];
    const float* g0_W   = (const float*)d_in[14];
    const float* g0_as  = (const float*)d_in[15];
    const float* g0_ad  = (const float*)d_in[16];
    const float* g0_bias= (const float*)d_in[17];
    const float* g1_W   = (const float*)d_in[18];
    const float* g1_as  = (const float*)d_in[19];
    const float* g1_ad  = (const float*)d_in[20];
    const float* g1_bias= (const float*)d_in[21];
    const float* idp_W  = (const float*)d_in[22];
    const float* idp_b  = (const float*)d_in[23];
    const float* idp_a  = (const float*)d_in[24];
    const float* cls_W  = (const float*)d_in[25];
    const float* cls_b  = (const float*)d_in[26];
    float* out = (float*)d_out;

    // workspace carve (256B aligned)
    char* p = (char*)d_ws;
    auto alloc = [&](size_t bytes) -> void* {
        void* r = (void*)p;
        p += (bytes + 255) & ~(size_t)255;
        return r;
    };
    int*   deg     = (int*)alloc((size_t)N_NODES * 4);
    int*   cursor  = (int*)alloc((size_t)N_NODES * 4);
    int*   row_off = (int*)alloc((size_t)(N_NODES + 1) * 4);
    int*   col     = (int*)alloc((size_t)N_EDGES * 4);
    int*   gstart  = (int*)alloc((size_t)(NGRAPH + 1) * 4);
    int*   bsum    = (int*)alloc((size_t)SCB * 4);
    int*   boff    = (int*)alloc((size_t)SCB * 4);
    float* es      = (float*)alloc((size_t)N_NODES * HEADS * 4);
    float* edv     = (float*)alloc((size_t)N_NODES * HEADS * 4);
    float* pool    = (float*)alloc((size_t)NGRAPH * HID * 4);
    bf16*  hA      = (bf16*)alloc((size_t)MPAD * HID * 2);
    bf16*  hB      = (bf16*)alloc((size_t)MPAD * HID * 2);
    // union: acat0 (MPAD*128 bf16), acat1 (MPAD*256 bf16), xw (MPAD*512 bf16)
    bf16*  u       = (bf16*)alloc((size_t)MPAD * (HEADS * HID) * 2);
    bf16*  acat0   = u;
    bf16*  acat1   = u;
    bf16*  xw      = u;
    // bf16 transposed weights
    bf16*  s0t     = (bf16*)alloc((size_t)128 * 128 * 2);
    bf16*  s1t     = (bf16*)alloc((size_t)128 * 256 * 2);
    bf16*  g0t     = (bf16*)alloc((size_t)512 * 128 * 2);
    bf16*  g1t     = (bf16*)alloc((size_t)512 * 128 * 2);
    bf16*  idpt    = (bf16*)alloc((size_t)3 * 128 * 128 * 2);

    hipMemsetAsync(deg, 0, (size_t)N_NODES * 4, stream);
    hipMemsetAsync(cursor, 0, (size_t)N_NODES * 4, stream);
    hipMemsetAsync(pool, 0, (size_t)NGRAPH * HID * 4, stream);

    // weight prep + CSR build + graph bounds
    k_prep<<<(229376 + 255) / 256, 256, 0, stream>>>(s0_Wl, s0_Wr, s1_Wl, s1_Wr,
                                                     g0_W, g1_W, idp_W,
                                                     s0t, s1t, g0t, g1t, idpt);
    k_count<<<(N_EDGES + 255) / 256, 256, 0, stream>>>(ei, deg);
    k_scan1<<<NSB, SCB, 0, stream>>>(deg, row_off, bsum);
    k_scan2<<<1, SCB, 0, stream>>>(bsum, boff);
    k_scan3<<<(N_NODES + 255) / 256, 256, 0, stream>>>(row_off, boff);
    k_fill<<<(N_EDGES + 255) / 256, 256, 0, stream>>>(ei, row_off, cursor, col);
    k_bounds<<<(N_NODES + 255) / 256, 256, 0, stream>>>(batch, gstart);

    const int MB = (N_NODES + 63) / 64;   // 782 row-blocks

    // SAGE 0
    k_sage_agg_f32<<<N_NODES, DIN, 0, stream>>>(x, row_off, col, acat0);
    k_gemm<128, 8, 1><<<dim3(MB, 1), 256, 0, stream>>>(
        acat0, s0t, hA, N_NODES, HID,
        s0_b, bn_g + 0 * HID, bn_b + 0 * HID, bn_m + 0 * HID, bn_v + 0 * HID, pre_a + 0 * HID);

    // SAGE 1
    k_sage_agg_bf<<<N_NODES, 64, 0, stream>>>(hA, row_off, col, acat1);
    k_gemm<256, 8, 1><<<dim3(MB, 1), 256, 0, stream>>>(
        acat1, s1t, hB, N_NODES, HID,
        s1_b, bn_g + 1 * HID, bn_b + 1 * HID, bn_m + 1 * HID, bn_v + 1 * HID, pre_a + 1 * HID);

    // GAT 0
    k_gemm<128, 8, 0><<<dim3(MB, 4), 256, 0, stream>>>(
        hB, g0t, xw, N_NODES, HEADS * HID, nullptr, nullptr, nullptr, nullptr, nullptr, nullptr);
    k_gat_scores<<<(N_NODES * HEADS) / 4, 256, 0, stream>>>(xw, g0_as, g0_ad, es, edv);
    k_gat_agg<<<N_NODES / 4, 256, 0, stream>>>(
        xw, es, edv, row_off, col, g0_bias,
        bn_g + 2 * HID, bn_b + 2 * HID, bn_m + 2 * HID, bn_v + 2 * HID, pre_a + 2 * HID, hA);

    // GAT 1
    k_gemm<128, 8, 0><<<dim3(MB, 4), 256, 0, stream>>>(
        hA, g1t, xw, N_NODES, HEADS * HID, nullptr, nullptr, nullptr, nullptr, nullptr, nullptr);
    k_gat_scores<<<(N_NODES * HEADS) / 4, 256, 0, stream>>>(xw, g1_as, g1_ad, es, edv);
    k_gat_agg<<<N_NODES / 4, 256, 0, stream>>>(
        xw, es, edv, row_off, col, g1_bias,
        bn_g + 3 * HID, bn_b + 3 * HID, bn_m + 3 * HID, bn_v + 3 * HID, pre_a + 3 * HID, hB);

    // IDP MLP
    k_gemm<128, 8, 2><<<dim3(MB, 1), 256, 0, stream>>>(
        hB, idpt + 0 * 16384, hA, N_NODES, HID,
        idp_b + 0 * HID, nullptr, nullptr, nullptr, nullptr, idp_a + 0 * HID);
    k_gemm<128, 8, 2><<<dim3(MB, 1), 256, 0, stream>>>(
        hA, idpt + 1 * 16384, hB, N_NODES, HID,
        idp_b + 1 * HID, nullptr, nullptr, nullptr, nullptr, idp_a + 1 * HID);
    k_gemm<128, 8, 3><<<dim3(MB, 1), 256, 0, stream>>>(
        hB, idpt + 2 * 16384, hA, N_NODES, HID,
        idp_b + 2 * HID, nullptr, nullptr, nullptr, nullptr, nullptr);

    // global mean pool + classifier
    k_pool<<<dim3(NGRAPH, PSEG), 64, 0, stream>>>(hA, gstart, pool);
    k_cls<<<1, NGRAPH * NCLS, 0, stream>>>(pool, gstart, cls_W, cls_b, out);
}

// Round 9
// 802.306 us; speedup vs baseline: 1.2832x; 1.0868x over previous
//
#include <hip/hip_runtime.h>
#include <hip/hip_bf16.h>
#include <math.h>

// Problem constants (match reference)
#define N_NODES 50000
#define N_EDGES 800000
#define DIN     64
#define HID     128
#define HEADS   4
#define NGRAPH  64
#define NCLS    8
#define EPSB    1e-5f
#define SLOPE   0.2f
#define PSEG    16               // pooling segments per graph
#define MAXC4   64               // gat_agg edge-chunk (one lane per edge)

#define SCB     256                            // scan block size
#define NSB     ((N_NODES + SCB - 1) / SCB)    // 196 scan blocks

#define MPAD    (N_NODES + 64)   // row padding for 64-row GEMM tiles
#define TPAD    136              // LDS tile row pad (128+8): 2-way b128 conflicts only

typedef __hip_bfloat16 bf16;
typedef __attribute__((ext_vector_type(8))) short short8;
typedef __attribute__((ext_vector_type(4))) float f32x4;

__device__ __forceinline__ float b2f(bf16 v) { return __bfloat162float(v); }
__device__ __forceinline__ bf16  f2b(float v) { return __float2bfloat16(v); }
__device__ __forceinline__ float lo_f(unsigned v) {
    unsigned u = v << 16; return __builtin_bit_cast(float, u);
}
__device__ __forceinline__ float hi_f(unsigned v) {
    unsigned u = v & 0xffff0000u; return __builtin_bit_cast(float, u);
}
__device__ __forceinline__ unsigned packbf(float lo, float hi) {
    unsigned l = (unsigned)__builtin_bit_cast(unsigned short, __float2bfloat16(lo));
    unsigned h = (unsigned)__builtin_bit_cast(unsigned short, __float2bfloat16(hi));
    return (h << 16) | l;
}

// ---------------- CSR build (+ graph bounds fused) ----------------
__global__ void k_count_bounds(const int* __restrict__ ei, int* __restrict__ deg,
                               const int* __restrict__ batch, int* __restrict__ gstart) {
    int e = blockIdx.x * 256 + threadIdx.x;
    if (e < N_EDGES) atomicAdd(&deg[ei[N_EDGES + e]], 1);
    int i = e;
    if (i < N_NODES) {
        int b = batch[i];
        int prev = (i == 0) ? -1 : batch[i - 1];
        for (int g = prev + 1; g <= b; ++g) gstart[g] = i;
        if (i == N_NODES - 1)
            for (int g = b + 1; g <= NGRAPH; ++g) gstart[g] = N_NODES;
    }
}

// hierarchical scan
__global__ void k_scan1(const int* __restrict__ deg, int* __restrict__ row_off,
                        int* __restrict__ bsum) {
    __shared__ int sm[SCB];
    int b = blockIdx.x, t = threadIdx.x;
    int i = b * SCB + t;
    int v = (i < N_NODES) ? deg[i] : 0;
    sm[t] = v;
    __syncthreads();
    for (int off = 1; off < SCB; off <<= 1) {
        int x = (t >= off) ? sm[t - off] : 0;
        __syncthreads();
        sm[t] += x;
        __syncthreads();
    }
    if (i < N_NODES) row_off[i + 1] = sm[t];
    if (t == SCB - 1) bsum[b] = sm[t];
}

__global__ void k_scan2(const int* __restrict__ bsum, int* __restrict__ boff) {
    __shared__ int sm[SCB];
    int t = threadIdx.x;
    int v = (t < NSB) ? bsum[t] : 0;
    sm[t] = v;
    __syncthreads();
    for (int off = 1; off < SCB; off <<= 1) {
        int x = (t >= off) ? sm[t - off] : 0;
        __syncthreads();
        sm[t] += x;
        __syncthreads();
    }
    boff[t] = sm[t] - v;   // exclusive
}

__global__ void k_scan3(int* __restrict__ row_off, const int* __restrict__ boff) {
    int i = blockIdx.x * 256 + threadIdx.x;
    if (i == 0) row_off[0] = 0;
    if (i < N_NODES) row_off[i + 1] += boff[i >> 8];
}

__global__ void k_fill(const int* __restrict__ ei, const int* __restrict__ row_off,
                       int* __restrict__ cursor, int* __restrict__ col) {
    int e = blockIdx.x * 256 + threadIdx.x;
    if (e < N_EDGES) {
        int s = ei[e], d = ei[N_EDGES + e];
        int pos = atomicAdd(&cursor[d], 1);
        col[row_off[d] + pos] = s;
    }
}

// ---------------- weight prep: convert to bf16, transposed (Bt[n][k]) ----------------
__global__ void k_prep(const float* __restrict__ s0Wl, const float* __restrict__ s0Wr,
                       const float* __restrict__ s1Wl, const float* __restrict__ s1Wr,
                       const float* __restrict__ g0W,  const float* __restrict__ g1W,
                       const float* __restrict__ idpW,
                       bf16* __restrict__ s0t, bf16* __restrict__ s1t,
                       bf16* __restrict__ g0t, bf16* __restrict__ g1t,
                       bf16* __restrict__ idpt) {
    int t = blockIdx.x * 256 + threadIdx.x;
    if (t < 16384) { int n = t >> 7, k = t & 127;
        s0t[t] = f2b(k < 64 ? s0Wl[k * 128 + n] : s0Wr[(k - 64) * 128 + n]); return; }
    t -= 16384;
    if (t < 32768) { int n = t >> 8, k = t & 255;
        s1t[t] = f2b(k < 128 ? s1Wl[k * 128 + n] : s1Wr[(k - 128) * 128 + n]); return; }
    t -= 32768;
    if (t < 65536) { int n = t >> 7, k = t & 127; g0t[t] = f2b(g0W[k * 512 + n]); return; }
    t -= 65536;
    if (t < 65536) { int n = t >> 7, k = t & 127; g1t[t] = f2b(g1W[k * 512 + n]); return; }
    t -= 65536;
    if (t < 49152) { int l = t >> 14, r = t & 16383; int n = r >> 7, k = r & 127;
        idpt[t] = f2b(idpW[l * 16384 + k * 128 + n]); }
}

// ---------------- SAGE mean-aggregate + concat self features ----------------
__global__ void k_sage_agg_f32(const float* __restrict__ xin, const int* __restrict__ row_off,
                               const int* __restrict__ col, bf16* __restrict__ acat) {
    int i = blockIdx.x;
    int c = threadIdx.x;  // 64
    int s0 = row_off[i], s1 = row_off[i + 1];
    float acc = 0.f;
    for (int j = s0; j < s1; ++j)
        acc += xin[(size_t)col[j] * DIN + c];
    acat[(size_t)i * (2 * DIN) + c]       = f2b(acc / fmaxf((float)(s1 - s0), 1.0f));
    acat[(size_t)i * (2 * DIN) + DIN + c] = f2b(xin[(size_t)i * DIN + c]);
}

__global__ void k_sage_agg_bf(const bf16* __restrict__ xin, const int* __restrict__ row_off,
                              const int* __restrict__ col, bf16* __restrict__ acat) {
    int i = blockIdx.x;
    int c = threadIdx.x;  // 64 lanes, channels 2c,2c+1
    int s0 = row_off[i], s1 = row_off[i + 1];
    const unsigned* xb = (const unsigned*)xin;
    float a0 = 0.f, a1 = 0.f;
    for (int j = s0; j < s1; ++j) {
        unsigned v = xb[(size_t)col[j] * (HID / 2) + c];
        a0 += lo_f(v); a1 += hi_f(v);
    }
    float inv = 1.0f / fmaxf((float)(s1 - s0), 1.0f);
    acat[(size_t)i * (2 * HID) + 2 * c]     = f2b(a0 * inv);
    acat[(size_t)i * (2 * HID) + 2 * c + 1] = f2b(a1 * inv);
    ((unsigned*)acat)[(size_t)i * HID + (HID / 2) + c] = xb[(size_t)i * (HID / 2) + c];
}

// ---------------- MFMA GEMM: C[M x Nc] = A[M x K] @ Bt^T, fused epilogue ----------------
// EPI: 0=none  1=bias+BN+PReLU  2=bias+PReLU  3=bias  4=store + GAT scores (head=blockIdx.y)
template <int K, int NT, int EPI>
__global__ __launch_bounds__(256) void k_gemm(
        const bf16* __restrict__ A, const bf16* __restrict__ Bt, bf16* __restrict__ C,
        int M, int Nc,
        const float* __restrict__ bias, const float* __restrict__ bng,
        const float* __restrict__ bnb,  const float* __restrict__ bnm,
        const float* __restrict__ bnv,  const float* __restrict__ pa,
        const float* __restrict__ asrc, const float* __restrict__ adst,
        float* __restrict__ es, float* __restrict__ ed) {
    int wave = threadIdx.x >> 6, lane = threadIdx.x & 63;
    int ln = lane & 15, q = lane >> 4;
    int m0 = blockIdx.x * 64 + wave * 16;
    int n0 = blockIdx.y * (NT * 16);
    const bf16* arow = A + (size_t)(m0 + ln) * K + q * 8;

    f32x4 acc[NT];
#pragma unroll
    for (int t = 0; t < NT; ++t) acc[t] = (f32x4){0.f, 0.f, 0.f, 0.f};

#pragma unroll
    for (int k = 0; k < K; k += 32) {
        short8 a = *(const short8*)(const void*)(arow + k);
#pragma unroll
        for (int t = 0; t < NT; ++t) {
            short8 b = *(const short8*)(const void*)(Bt + (size_t)(n0 + t * 16 + ln) * K + k + q * 8);
            acc[t] = __builtin_amdgcn_mfma_f32_16x16x32_bf16(a, b, acc[t], 0, 0, 0);
        }
    }

#pragma unroll
    for (int t = 0; t < NT; ++t) {
        int cidx = n0 + t * 16 + ln;
        float bi = 0.f, g = 1.f, bb = 0.f, mm = 0.f, iv = 1.f, al = 1.f;
        if (EPI == 1 || EPI == 2 || EPI == 3) bi = bias[cidx];
        if (EPI == 1) { g = bng[cidx]; bb = bnb[cidx]; mm = bnm[cidx]; iv = rsqrtf(bnv[cidx] + EPSB); }
        if (EPI == 1 || EPI == 2) al = pa[cidx];
#pragma unroll
        for (int r = 0; r < 4; ++r) {
            int mr = m0 + q * 4 + r;
            if (mr < M) {
                float v = acc[t][r] + bi;
                if (EPI == 1) v = (v - mm) * iv * g + bb;
                if (EPI == 1 || EPI == 2) v = v >= 0.f ? v : al * v;
                C[(size_t)mr * Nc + cidx] = f2b(v);
            }
        }
    }

    if (EPI == 4) {
        // GAT scores from fp32 acc: es/ed[row][head] = sum_c xw*a
        int head = blockIdx.y;
        float asv[NT], adv[NT];
#pragma unroll
        for (int t = 0; t < NT; ++t) {
            asv[t] = asrc[head * HID + t * 16 + ln];
            adv[t] = adst[head * HID + t * 16 + ln];
        }
#pragma unroll
        for (int r = 0; r < 4; ++r) {
            float ps = 0.f, pd = 0.f;
#pragma unroll
            for (int t = 0; t < NT; ++t) { ps += acc[t][r] * asv[t]; pd += acc[t][r] * adv[t]; }
#pragma unroll
            for (int off = 1; off < 16; off <<= 1) {
                ps += __shfl_xor(ps, off, 16);
                pd += __shfl_xor(pd, off, 16);
            }
            int mr = m0 + q * 4 + r;
            if (ln == 0 && mr < M) {
                es[mr * HEADS + head] = ps;
                ed[mr * HEADS + head] = pd;
            }
        }
    }
}

// ---------------- fused 3-layer IDP MLP (wave-private LDS transpose) ----------------
__global__ __launch_bounds__(256) void k_mlp3(
        const bf16* __restrict__ A,
        const bf16* __restrict__ W0t, const bf16* __restrict__ W1t,
        const bf16* __restrict__ W2t,
        const float* __restrict__ b0, const float* __restrict__ a0,
        const float* __restrict__ b1, const float* __restrict__ a1,
        const float* __restrict__ b2,
        bf16* __restrict__ outp, int M) {
    __shared__ bf16 tile[4][16][TPAD];
    int wave = threadIdx.x >> 6, lane = threadIdx.x & 63;
    int ln = lane & 15, q = lane >> 4;
    int m0 = blockIdx.x * 64 + wave * 16;
    bf16* myt = &tile[wave][0][0];

    f32x4 acc[8];
#pragma unroll
    for (int t = 0; t < 8; ++t) acc[t] = (f32x4){0.f, 0.f, 0.f, 0.f};

    // layer 0: A from global
    {
        const bf16* arow = A + (size_t)(m0 + ln) * HID + q * 8;
#pragma unroll
        for (int k = 0; k < HID; k += 32) {
            short8 a = *(const short8*)(const void*)(arow + k);
#pragma unroll
            for (int t = 0; t < 8; ++t) {
                short8 b = *(const short8*)(const void*)(W0t + (size_t)(t * 16 + ln) * HID + k + q * 8);
                acc[t] = __builtin_amdgcn_mfma_f32_16x16x32_bf16(a, b, acc[t], 0, 0, 0);
            }
        }
        // prelu epilogue -> LDS tile (wave-private; same-wave order, no barrier)
#pragma unroll
        for (int t = 0; t < 8; ++t) {
            int c = t * 16 + ln;
            float bi = b0[c], al = a0[c];
#pragma unroll
            for (int r = 0; r < 4; ++r) {
                float v = acc[t][r] + bi;
                v = v >= 0.f ? v : al * v;
                myt[(q * 4 + r) * TPAD + c] = f2b(v);
            }
        }
    }
    // layer 1: A from LDS
    {
#pragma unroll
        for (int t = 0; t < 8; ++t) acc[t] = (f32x4){0.f, 0.f, 0.f, 0.f};
#pragma unroll
        for (int k = 0; k < HID; k += 32) {
            short8 a = *(const short8*)(const void*)(&myt[ln * TPAD + k + q * 8]);
#pragma unroll
            for (int t = 0; t < 8; ++t) {
                short8 b = *(const short8*)(const void*)(W1t + (size_t)(t * 16 + ln) * HID + k + q * 8);
                acc[t] = __builtin_amdgcn_mfma_f32_16x16x32_bf16(a, b, acc[t], 0, 0, 0);
            }
        }
#pragma unroll
        for (int t = 0; t < 8; ++t) {
            int c = t * 16 + ln;
            float bi = b1[c], al = a1[c];
#pragma unroll
            for (int r = 0; r < 4; ++r) {
                float v = acc[t][r] + bi;
                v = v >= 0.f ? v : al * v;
                myt[(q * 4 + r) * TPAD + c] = f2b(v);
            }
        }
    }
    // layer 2: A from LDS, bias only, store global
    {
#pragma unroll
        for (int t = 0; t < 8; ++t) acc[t] = (f32x4){0.f, 0.f, 0.f, 0.f};
#pragma unroll
        for (int k = 0; k < HID; k += 32) {
            short8 a = *(const short8*)(const void*)(&myt[ln * TPAD + k + q * 8]);
#pragma unroll
            for (int t = 0; t < 8; ++t) {
                short8 b = *(const short8*)(const void*)(W2t + (size_t)(t * 16 + ln) * HID + k + q * 8);
                acc[t] = __builtin_amdgcn_mfma_f32_16x16x32_bf16(a, b, acc[t], 0, 0, 0);
            }
        }
#pragma unroll
        for (int t = 0; t < 8; ++t) {
            int c = t * 16 + ln;
            float bi = b2[c];
#pragma unroll
            for (int r = 0; r < 4; ++r) {
                int mr = m0 + q * 4 + r;
                if (mr < M) outp[(size_t)mr * HID + c] = f2b(acc[t][r] + bi);
            }
        }
    }
}

// ---------------- GAT aggregation (unchanged from R8) ----------------
__global__ __launch_bounds__(256) void k_gat_agg(
        const bf16* __restrict__ xw, const float* __restrict__ es,
        const float* __restrict__ ed, const int* __restrict__ row_off,
        const int* __restrict__ col, const float* __restrict__ bias,
        const float* __restrict__ bng, const float* __restrict__ bnb,
        const float* __restrict__ bnm, const float* __restrict__ bnv,
        const float* __restrict__ pa,
        bf16* __restrict__ out) {
    __shared__ __align__(16) float sEx[4][MAXC4][HEADS];
    __shared__ int sCol[4][MAXC4];
    int w = threadIdx.x >> 6;
    int lane = threadIdx.x & 63;
    int i = blockIdx.x * 4 + w;          // grid = N/4 exactly
    int h = lane >> 4;
    const uint4*  xw4 = (const uint4*)xw;     // row = 64 uint4 (1 KB)
    const float4* es4 = (const float4*)es;
    float4 edi = ((const float4*)ed)[i];

    int s0 = row_off[i], s1 = row_off[i + 1];
    float den0 = 0.f, den1 = 0.f, den2 = 0.f, den3 = 0.f;
    float a[8];
#pragma unroll
    for (int j = 0; j < 8; ++j) a[j] = 0.f;

    {   // self loop
        float4 ev = es4[i];
        float e0 = ev.x + edi.x; e0 = e0 >= 0.f ? e0 : SLOPE * e0; float x0 = expf(e0);
        float e1 = ev.y + edi.y; e1 = e1 >= 0.f ? e1 : SLOPE * e1; float x1 = expf(e1);
        float e2 = ev.z + edi.z; e2 = e2 >= 0.f ? e2 : SLOPE * e2; float x2 = expf(e2);
        float e3 = ev.w + edi.w; e3 = e3 >= 0.f ? e3 : SLOPE * e3; float x3 = expf(e3);
        if (lane == 0) { den0 = x0; den1 = x1; den2 = x2; den3 = x3; }
        float exh = h == 0 ? x0 : h == 1 ? x1 : h == 2 ? x2 : x3;
        uint4 v = xw4[(size_t)i * 64 + lane];
        a[0] += exh * lo_f(v.x); a[1] += exh * hi_f(v.x);
        a[2] += exh * lo_f(v.y); a[3] += exh * hi_f(v.y);
        a[4] += exh * lo_f(v.z); a[5] += exh * hi_f(v.z);
        a[6] += exh * lo_f(v.w); a[7] += exh * hi_f(v.w);
    }
    for (int c0 = s0; c0 < s1; c0 += MAXC4) {
        int cnt = min(MAXC4, s1 - c0);
        if (lane < cnt) {
            int s = col[c0 + lane];
            float4 ev = es4[s];
            float e0 = ev.x + edi.x; e0 = e0 >= 0.f ? e0 : SLOPE * e0; float x0 = expf(e0);
            float e1 = ev.y + edi.y; e1 = e1 >= 0.f ? e1 : SLOPE * e1; float x1 = expf(e1);
            float e2 = ev.z + edi.z; e2 = e2 >= 0.f ? e2 : SLOPE * e2; float x2 = expf(e2);
            float e3 = ev.w + edi.w; e3 = e3 >= 0.f ? e3 : SLOPE * e3; float x3 = expf(e3);
            den0 += x0; den1 += x1; den2 += x2; den3 += x3;
            sCol[w][lane] = s;
            f32x4 xv = {x0, x1, x2, x3};
            *(f32x4*)(&sEx[w][lane][0]) = xv;
        }
        // same-wave LDS write->read: program order, no block barrier needed
        for (int e = 0; e < cnt; ++e) {
            float ex = sEx[w][e][h];
            int s = sCol[w][e];
            uint4 v = xw4[(size_t)s * 64 + lane];
            a[0] += ex * lo_f(v.x); a[1] += ex * hi_f(v.x);
            a[2] += ex * lo_f(v.y); a[3] += ex * hi_f(v.y);
            a[4] += ex * lo_f(v.z); a[5] += ex * hi_f(v.z);
            a[6] += ex * lo_f(v.w); a[7] += ex * hi_f(v.w);
        }
    }
    for (int off = 1; off < 64; off <<= 1) {
        den0 += __shfl_xor(den0, off, 64);
        den1 += __shfl_xor(den1, off, 64);
        den2 += __shfl_xor(den2, off, 64);
        den3 += __shfl_xor(den3, off, 64);
    }
    float den = h == 0 ? den0 : h == 1 ? den1 : h == 2 ? den2 : den3;
    float inv = 1.0f / den;
    float m[8];
#pragma unroll
    for (int j = 0; j < 8; ++j) m[j] = a[j] * inv;
#pragma unroll
    for (int j = 0; j < 8; ++j) {
        m[j] += __shfl_xor(m[j], 16, 64);
        m[j] += __shfl_xor(m[j], 32, 64);
    }
    if (lane < 16) {
        int cb = lane * 8;
        float r[8];
#pragma unroll
        for (int j = 0; j < 8; ++j) {
            int c = cb + j;
            float v = 0.25f * m[j] + bias[c];
            v = (v - bnm[c]) * rsqrtf(bnv[c] + EPSB) * bng[c] + bnb[c];
            float al = pa[c];
            r[j] = v >= 0.f ? v : al * v;
        }
        uint4 o;
        o.x = packbf(r[0], r[1]); o.y = packbf(r[2], r[3]);
        o.z = packbf(r[4], r[5]); o.w = packbf(r[6], r[7]);
        ((uint4*)out)[(size_t)i * 16 + lane] = o;
    }
}

// ---------------- pool / classifier ----------------
__global__ void k_pool(const bf16* __restrict__ h, const int* __restrict__ gstart,
                       float* __restrict__ pool) {
    int g = blockIdx.x, s = blockIdx.y;
    int c = threadIdx.x;   // 64 lanes, channels 2c,2c+1
    int b0 = gstart[g], b1 = gstart[g + 1];
    int len = b1 - b0;
    if (len <= 0) return;
    int per = (len + PSEG - 1) / PSEG;
    int r0 = b0 + s * per;
    int r1 = min(r0 + per, b1);
    if (r0 >= r1) return;
    const unsigned* hb = (const unsigned*)h;
    float a0 = 0.f, a1 = 0.f;
    for (int i = r0; i < r1; ++i) {
        unsigned v = hb[(size_t)i * (HID / 2) + c];
        a0 += lo_f(v); a1 += hi_f(v);
    }
    atomicAdd(&pool[g * HID + 2 * c], a0);
    atomicAdd(&pool[g * HID + 2 * c + 1], a1);
}

__global__ void k_cls(const float* __restrict__ pool, const int* __restrict__ gstart,
                      const float* __restrict__ W, const float* __restrict__ b,
                      float* __restrict__ out) {
    int t = threadIdx.x;            // 512 = 64*8
    int g = t / NCLS, n = t % NCLS;
    float ic = 1.0f / fmaxf((float)(gstart[g + 1] - gstart[g]), 1.0f);
    float acc = b[n];
    for (int k = 0; k < HID; ++k)
        acc += pool[g * HID + k] * ic * W[k * NCLS + n];
    out[g * NCLS + n] = acc;
}

// ---------------- launch ----------------
extern "C" void kernel_launch(void* const* d_in, const int* in_sizes, int n_in,
                              void* d_out, int out_size, void* d_ws, size_t ws_size,
                              hipStream_t stream) {
    const float* x      = (const float*)d_in[0];
    const int*   ei     = (const int*)d_in[1];
    const int*   batch  = (const int*)d_in[2];
    const float* s0_Wl  = (const float*)d_in[3];
    const float* s0_Wr  = (const float*)d_in[4];
    const float* s0_b   = (const float*)d_in[5];
    const float* s1_Wl  = (const float*)d_in[6];
    const float* s1_Wr  = (const float*)d_in[7];
    const float* s1_b   = (const float*)d_in[8];
    const float* bn_g   = (const float*)d_in[9];
    const float* bn_b   = (const float*)d_in[10];
    const float* bn_m   = (const float*)d_in[11];
    const float* bn_v   = (const float*)d_in[12];
    const float* pre_a  = (const float*)d_in[13];
    const float* g0_W   = (const float*)d_in[14];
    const float* g0_as  = (const float*)d_in[15];
    const float* g0_ad  = (const float*)d_in[16];
    const float* g0_bias= (const float*)d_in[17];
    const float* g1_W   = (const float*)d_in[18];
    const float* g1_as  = (const float*)d_in[19];
    const float* g1_ad  = (const float*)d_in[20];
    const float* g1_bias= (const float*)d_in[21];
    const float* idp_W  = (const float*)d_in[22];
    const float* idp_b  = (const float*)d_in[23];
    const float* idp_a  = (const float*)d_in[24];
    const float* cls_W  = (const float*)d_in[25];
    const float* cls_b  = (const float*)d_in[26];
    float* out = (float*)d_out;

    // workspace carve (256B aligned)
    char* p = (char*)d_ws;
    auto alloc = [&](size_t bytes) -> void* {
        void* r = (void*)p;
        p += (bytes + 255) & ~(size_t)255;
        return r;
    };
    int*   degcur  = (int*)alloc((size_t)2 * N_NODES * 4);   // deg | cursor (one memset)
    int*   deg     = degcur;
    int*   cursor  = degcur + N_NODES;
    int*   row_off = (int*)alloc((size_t)(N_NODES + 1) * 4);
    int*   col     = (int*)alloc((size_t)N_EDGES * 4);
    int*   gstart  = (int*)alloc((size_t)(NGRAPH + 1) * 4);
    int*   bsum    = (int*)alloc((size_t)SCB * 4);
    int*   boff    = (int*)alloc((size_t)SCB * 4);
    float* es      = (float*)alloc((size_t)N_NODES * HEADS * 4);
    float* edv     = (float*)alloc((size_t)N_NODES * HEADS * 4);
    float* pool    = (float*)alloc((size_t)NGRAPH * HID * 4);
    bf16*  hA      = (bf16*)alloc((size_t)MPAD * HID * 2);
    bf16*  hB      = (bf16*)alloc((size_t)MPAD * HID * 2);
    // union: acat0 (MPAD*128 bf16), acat1 (MPAD*256 bf16), xw (MPAD*512 bf16)
    bf16*  u       = (bf16*)alloc((size_t)MPAD * (HEADS * HID) * 2);
    bf16*  acat0   = u;
    bf16*  acat1   = u;
    bf16*  xw      = u;
    // bf16 transposed weights
    bf16*  s0t     = (bf16*)alloc((size_t)128 * 128 * 2);
    bf16*  s1t     = (bf16*)alloc((size_t)128 * 256 * 2);
    bf16*  g0t     = (bf16*)alloc((size_t)512 * 128 * 2);
    bf16*  g1t     = (bf16*)alloc((size_t)512 * 128 * 2);
    bf16*  idpt    = (bf16*)alloc((size_t)3 * 128 * 128 * 2);

    hipMemsetAsync(degcur, 0, (size_t)2 * N_NODES * 4, stream);
    hipMemsetAsync(pool, 0, (size_t)NGRAPH * HID * 4, stream);

    // weight prep + CSR build + graph bounds
    k_prep<<<(229376 + 255) / 256, 256, 0, stream>>>(s0_Wl, s0_Wr, s1_Wl, s1_Wr,
                                                     g0_W, g1_W, idp_W,
                                                     s0t, s1t, g0t, g1t, idpt);
    k_count_bounds<<<(N_EDGES + 255) / 256, 256, 0, stream>>>(ei, deg, batch, gstart);
    k_scan1<<<NSB, SCB, 0, stream>>>(deg, row_off, bsum);
    k_scan2<<<1, SCB, 0, stream>>>(bsum, boff);
    k_scan3<<<(N_NODES + 255) / 256, 256, 0, stream>>>(row_off, boff);
    k_fill<<<(N_EDGES + 255) / 256, 256, 0, stream>>>(ei, row_off, cursor, col);

    const int MB = (N_NODES + 63) / 64;   // 782 row-blocks

    // SAGE 0
    k_sage_agg_f32<<<N_NODES, DIN, 0, stream>>>(x, row_off, col, acat0);
    k_gemm<128, 8, 1><<<dim3(MB, 1), 256, 0, stream>>>(
        acat0, s0t, hA, N_NODES, HID,
        s0_b, bn_g + 0 * HID, bn_b + 0 * HID, bn_m + 0 * HID, bn_v + 0 * HID, pre_a + 0 * HID,
        nullptr, nullptr, nullptr, nullptr);

    // SAGE 1
    k_sage_agg_bf<<<N_NODES, 64, 0, stream>>>(hA, row_off, col, acat1);
    k_gemm<256, 8, 1><<<dim3(MB, 1), 256, 0, stream>>>(
        acat1, s1t, hB, N_NODES, HID,
        s1_b, bn_g + 1 * HID, bn_b + 1 * HID, bn_m + 1 * HID, bn_v + 1 * HID, pre_a + 1 * HID,
        nullptr, nullptr, nullptr, nullptr);

    // GAT 0 (gemm fuses score computation)
    k_gemm<128, 8, 4><<<dim3(MB, 4), 256, 0, stream>>>(
        hB, g0t, xw, N_NODES, HEADS * HID,
        nullptr, nullptr, nullptr, nullptr, nullptr, nullptr,
        g0_as, g0_ad, es, edv);
    k_gat_agg<<<N_NODES / 4, 256, 0, stream>>>(
        xw, es, edv, row_off, col, g0_bias,
        bn_g + 2 * HID, bn_b + 2 * HID, bn_m + 2 * HID, bn_v + 2 * HID, pre_a + 2 * HID, hA);

    // GAT 1
    k_gemm<128, 8, 4><<<dim3(MB, 4), 256, 0, stream>>>(
        hA, g1t, xw, N_NODES, HEADS * HID,
        nullptr, nullptr, nullptr, nullptr, nullptr, nullptr,
        g1_as, g1_ad, es, edv);
    k_gat_agg<<<N_NODES / 4, 256, 0, stream>>>(
        xw, es, edv, row_off, col, g1_bias,
        bn_g + 3 * HID, bn_b + 3 * HID, bn_m + 3 * HID, bn_v + 3 * HID, pre_a + 3 * HID, hB);

    // IDP MLP (3 layers fused)
    k_mlp3<<<MB, 256, 0, stream>>>(
        hB, idpt + 0 * 16384, idpt + 1 * 16384, idpt + 2 * 16384,
        idp_b + 0 * HID, idp_a + 0 * HID,
        idp_b + 1 * HID, idp_a + 1 * HID,
        idp_b + 2 * HID, hA, N_NODES);

    // global mean pool + classifier
    k_pool<<<dim3(NGRAPH, PSEG), 64, 0, stream>>>(hA, gstart, pool);
    k_cls<<<1, NGRAPH * NCLS, 0, stream>>>(pool, gstart, cls_W, cls_b, out);
}

// Round 10
// 667.639 us; speedup vs baseline: 1.5420x; 1.2017x over previous
//
#include <hip/hip_runtime.h>
#include <hip/hip_bf16.h>
#include <math.h>

// Problem constants (match reference)
#define N_NODES 50000
#define N_EDGES 800000
#define DIN     64
#define HID     128
#define HEADS   4
#define NGRAPH  64
#define NCLS    8
#define EPSB    1e-5f
#define SLOPE   0.2f
#define PSEG    16               // pooling segments per graph
#define MAXC4   64               // edge-chunk (one lane per edge)
#define FP8S    16.0f            // xw fp8 encode scale
#define FP8SI   (0.25f / FP8S)   // head-mean * decode scale

#define SCB     256                            // scan block size
#define NSB     ((N_NODES + SCB - 1) / SCB)    // 196 scan blocks

#define MPAD    (N_NODES + 64)   // row padding for 64-row GEMM tiles
#define TPAD    136              // LDS tile row pad (128+8)

typedef __hip_bfloat16 bf16;
typedef __attribute__((ext_vector_type(8))) short short8;
typedef __attribute__((ext_vector_type(4))) float f32x4;
typedef __attribute__((ext_vector_type(2))) float f32x2;

__device__ __forceinline__ float b2f(bf16 v) { return __bfloat162float(v); }
__device__ __forceinline__ bf16  f2b(float v) { return __float2bfloat16(v); }
__device__ __forceinline__ float lo_f(unsigned v) {
    unsigned u = v << 16; return __builtin_bit_cast(float, u);
}
__device__ __forceinline__ float hi_f(unsigned v) {
    unsigned u = v & 0xffff0000u; return __builtin_bit_cast(float, u);
}
__device__ __forceinline__ unsigned packbf(float lo, float hi) {
    unsigned l = (unsigned)__builtin_bit_cast(unsigned short, __float2bfloat16(lo));
    unsigned h = (unsigned)__builtin_bit_cast(unsigned short, __float2bfloat16(hi));
    return (h << 16) | l;
}

// ---------------- CSR build (+ graph bounds fused) ----------------
__global__ void k_count_bounds(const int* __restrict__ ei, int* __restrict__ deg,
                               const int* __restrict__ batch, int* __restrict__ gstart) {
    int e = blockIdx.x * 256 + threadIdx.x;
    if (e < N_EDGES) atomicAdd(&deg[ei[N_EDGES + e]], 1);
    int i = e;
    if (i < N_NODES) {
        int b = batch[i];
        int prev = (i == 0) ? -1 : batch[i - 1];
        for (int g = prev + 1; g <= b; ++g) gstart[g] = i;
        if (i == N_NODES - 1)
            for (int g = b + 1; g <= NGRAPH; ++g) gstart[g] = N_NODES;
    }
}

// hierarchical scan
__global__ void k_scan1(const int* __restrict__ deg, int* __restrict__ row_off,
                        int* __restrict__ bsum) {
    __shared__ int sm[SCB];
    int b = blockIdx.x, t = threadIdx.x;
    int i = b * SCB + t;
    int v = (i < N_NODES) ? deg[i] : 0;
    sm[t] = v;
    __syncthreads();
    for (int off = 1; off < SCB; off <<= 1) {
        int x = (t >= off) ? sm[t - off] : 0;
        __syncthreads();
        sm[t] += x;
        __syncthreads();
    }
    if (i < N_NODES) row_off[i + 1] = sm[t];
    if (t == SCB - 1) bsum[b] = sm[t];
}

__global__ void k_scan2(const int* __restrict__ bsum, int* __restrict__ boff) {
    __shared__ int sm[SCB];
    int t = threadIdx.x;
    int v = (t < NSB) ? bsum[t] : 0;
    sm[t] = v;
    __syncthreads();
    for (int off = 1; off < SCB; off <<= 1) {
        int x = (t >= off) ? sm[t - off] : 0;
        __syncthreads();
        sm[t] += x;
        __syncthreads();
    }
    boff[t] = sm[t] - v;   // exclusive
}

__global__ void k_scan3(int* __restrict__ row_off, const int* __restrict__ boff) {
    int i = blockIdx.x * 256 + threadIdx.x;
    if (i == 0) row_off[0] = 0;
    if (i < N_NODES) row_off[i + 1] += boff[i >> 8];
}

__global__ void k_fill(const int* __restrict__ ei, const int* __restrict__ row_off,
                       int* __restrict__ cursor, int* __restrict__ col) {
    int e = blockIdx.x * 256 + threadIdx.x;
    if (e < N_EDGES) {
        int s = ei[e], d = ei[N_EDGES + e];
        int pos = atomicAdd(&cursor[d], 1);
        col[row_off[d] + pos] = s;
    }
}

// ---------------- weight prep: convert to bf16, transposed (Bt[n][k]) ----------------
__global__ void k_prep(const float* __restrict__ s0Wl, const float* __restrict__ s0Wr,
                       const float* __restrict__ s1Wl, const float* __restrict__ s1Wr,
                       const float* __restrict__ g0W,  const float* __restrict__ g1W,
                       const float* __restrict__ idpW,
                       bf16* __restrict__ s0t, bf16* __restrict__ s1t,
                       bf16* __restrict__ g0t, bf16* __restrict__ g1t,
                       bf16* __restrict__ idpt) {
    int t = blockIdx.x * 256 + threadIdx.x;
    if (t < 16384) { int n = t >> 7, k = t & 127;
        s0t[t] = f2b(k < 64 ? s0Wl[k * 128 + n] : s0Wr[(k - 64) * 128 + n]); return; }
    t -= 16384;
    if (t < 32768) { int n = t >> 8, k = t & 255;
        s1t[t] = f2b(k < 128 ? s1Wl[k * 128 + n] : s1Wr[(k - 128) * 128 + n]); return; }
    t -= 32768;
    if (t < 65536) { int n = t >> 7, k = t & 127; g0t[t] = f2b(g0W[k * 512 + n]); return; }
    t -= 65536;
    if (t < 65536) { int n = t >> 7, k = t & 127; g1t[t] = f2b(g1W[k * 512 + n]); return; }
    t -= 65536;
    if (t < 49152) { int l = t >> 14, r = t & 16383; int n = r >> 7, k = r & 127;
        idpt[t] = f2b(idpW[l * 16384 + k * 128 + n]); }
}

// ---------------- SAGE mean-aggregate + concat self (wave=node, col prefetch) ----------------
__global__ __launch_bounds__(256) void k_sage_agg_f32(
        const float* __restrict__ xin, const int* __restrict__ row_off,
        const int* __restrict__ col, bf16* __restrict__ acat) {
    __shared__ int sCol[4][MAXC4];
    int w = threadIdx.x >> 6, lane = threadIdx.x & 63;
    int i = blockIdx.x * 4 + w;
    int s0 = row_off[i], s1 = row_off[i + 1];
    float acc = 0.f;
    for (int c0 = s0; c0 < s1; c0 += MAXC4) {
        int cnt = min(MAXC4, s1 - c0);
        if (lane < cnt) sCol[w][lane] = col[c0 + lane];
        for (int e = 0; e < cnt; ++e)
            acc += xin[(size_t)sCol[w][e] * DIN + lane];
    }
    acat[(size_t)i * (2 * DIN) + lane]       = f2b(acc / fmaxf((float)(s1 - s0), 1.0f));
    acat[(size_t)i * (2 * DIN) + DIN + lane] = f2b(xin[(size_t)i * DIN + lane]);
}

__global__ __launch_bounds__(256) void k_sage_agg_bf(
        const bf16* __restrict__ xin, const int* __restrict__ row_off,
        const int* __restrict__ col, bf16* __restrict__ acat) {
    __shared__ int sCol[4][MAXC4];
    int w = threadIdx.x >> 6, lane = threadIdx.x & 63;
    int i = blockIdx.x * 4 + w;
    int s0 = row_off[i], s1 = row_off[i + 1];
    const unsigned* xb = (const unsigned*)xin;   // row = 64 uints
    float a0 = 0.f, a1 = 0.f;
    for (int c0 = s0; c0 < s1; c0 += MAXC4) {
        int cnt = min(MAXC4, s1 - c0);
        if (lane < cnt) sCol[w][lane] = col[c0 + lane];
        for (int e = 0; e < cnt; ++e) {
            unsigned v = xb[(size_t)sCol[w][e] * (HID / 2) + lane];
            a0 += lo_f(v); a1 += hi_f(v);
        }
    }
    float inv = 1.0f / fmaxf((float)(s1 - s0), 1.0f);
    unsigned* ao = (unsigned*)acat;              // row stride 128 uints
    ao[(size_t)i * HID + lane]              = packbf(a0 * inv, a1 * inv);
    ao[(size_t)i * HID + (HID / 2) + lane]  = xb[(size_t)i * (HID / 2) + lane];
}

// ---------------- MFMA GEMM: C = A @ Bt^T, fused epilogue ----------------
// EPI: 1=bias+BN+PReLU  4=fp8-store(scale 16) + GAT scores (head=blockIdx.y)
template <int K, int NT, int EPI>
__global__ __launch_bounds__(256) void k_gemm(
        const bf16* __restrict__ A, const bf16* __restrict__ Bt, void* __restrict__ Cp,
        int M, int Nc,
        const float* __restrict__ bias, const float* __restrict__ bng,
        const float* __restrict__ bnb,  const float* __restrict__ bnm,
        const float* __restrict__ bnv,  const float* __restrict__ pa,
        const float* __restrict__ asrc, const float* __restrict__ adst,
        float* __restrict__ es, float* __restrict__ ed) {
    int wave = threadIdx.x >> 6, lane = threadIdx.x & 63;
    int ln = lane & 15, q = lane >> 4;
    int m0 = blockIdx.x * 64 + wave * 16;
    int n0 = blockIdx.y * (NT * 16);
    const bf16* arow = A + (size_t)(m0 + ln) * K + q * 8;

    f32x4 acc[NT];
#pragma unroll
    for (int t = 0; t < NT; ++t) acc[t] = (f32x4){0.f, 0.f, 0.f, 0.f};

#pragma unroll
    for (int k = 0; k < K; k += 32) {
        short8 a = *(const short8*)(const void*)(arow + k);
#pragma unroll
        for (int t = 0; t < NT; ++t) {
            short8 b = *(const short8*)(const void*)(Bt + (size_t)(n0 + t * 16 + ln) * K + k + q * 8);
            acc[t] = __builtin_amdgcn_mfma_f32_16x16x32_bf16(a, b, acc[t], 0, 0, 0);
        }
    }

    if (EPI != 4) {
        bf16* C = (bf16*)Cp;
#pragma unroll
        for (int t = 0; t < NT; ++t) {
            int cidx = n0 + t * 16 + ln;
            float bi = bias[cidx];
            float g = bng[cidx], bb = bnb[cidx], mm = bnm[cidx];
            float iv = rsqrtf(bnv[cidx] + EPSB), al = pa[cidx];
#pragma unroll
            for (int r = 0; r < 4; ++r) {
                int mr = m0 + q * 4 + r;
                if (mr < M) {
                    float v = acc[t][r] + bi;
                    v = (v - mm) * iv * g + bb;
                    v = v >= 0.f ? v : al * v;
                    C[(size_t)mr * Nc + cidx] = f2b(v);
                }
            }
        }
    } else {
        // fp8 store (scale FP8S)
        unsigned char* C8 = (unsigned char*)Cp;
#pragma unroll
        for (int t = 0; t < NT; ++t) {
            int cidx = n0 + t * 16 + ln;
#pragma unroll
            for (int r = 0; r < 4; ++r) {
                int mr = m0 + q * 4 + r;
                if (mr < M) {
                    int enc = __builtin_amdgcn_cvt_pk_fp8_f32(acc[t][r] * FP8S, 0.f, 0, false);
                    C8[(size_t)mr * 512 + cidx] = (unsigned char)(enc & 0xff);
                }
            }
        }
        // GAT scores from fp32 acc
        int head = blockIdx.y;
        float asv[NT], adv[NT];
#pragma unroll
        for (int t = 0; t < NT; ++t) {
            asv[t] = asrc[head * HID + t * 16 + ln];
            adv[t] = adst[head * HID + t * 16 + ln];
        }
#pragma unroll
        for (int r = 0; r < 4; ++r) {
            float ps = 0.f, pd = 0.f;
#pragma unroll
            for (int t = 0; t < NT; ++t) { ps += acc[t][r] * asv[t]; pd += acc[t][r] * adv[t]; }
#pragma unroll
            for (int off = 1; off < 16; off <<= 1) {
                ps += __shfl_xor(ps, off, 16);
                pd += __shfl_xor(pd, off, 16);
            }
            int mr = m0 + q * 4 + r;
            if (ln == 0 && mr < M) {
                es[mr * HEADS + head] = ps;
                ed[mr * HEADS + head] = pd;
            }
        }
    }
}

// ---------------- fused 3-layer IDP MLP (wave-private LDS transpose) ----------------
__global__ __launch_bounds__(256) void k_mlp3(
        const bf16* __restrict__ A,
        const bf16* __restrict__ W0t, const bf16* __restrict__ W1t,
        const bf16* __restrict__ W2t,
        const float* __restrict__ b0, const float* __restrict__ a0,
        const float* __restrict__ b1, const float* __restrict__ a1,
        const float* __restrict__ b2,
        bf16* __restrict__ outp, int M) {
    __shared__ bf16 tile[4][16][TPAD];
    int wave = threadIdx.x >> 6, lane = threadIdx.x & 63;
    int ln = lane & 15, q = lane >> 4;
    int m0 = blockIdx.x * 64 + wave * 16;
    bf16* myt = &tile[wave][0][0];

    f32x4 acc[8];
#pragma unroll
    for (int t = 0; t < 8; ++t) acc[t] = (f32x4){0.f, 0.f, 0.f, 0.f};
    {
        const bf16* arow = A + (size_t)(m0 + ln) * HID + q * 8;
#pragma unroll
        for (int k = 0; k < HID; k += 32) {
            short8 a = *(const short8*)(const void*)(arow + k);
#pragma unroll
            for (int t = 0; t < 8; ++t) {
                short8 b = *(const short8*)(const void*)(W0t + (size_t)(t * 16 + ln) * HID + k + q * 8);
                acc[t] = __builtin_amdgcn_mfma_f32_16x16x32_bf16(a, b, acc[t], 0, 0, 0);
            }
        }
#pragma unroll
        for (int t = 0; t < 8; ++t) {
            int c = t * 16 + ln;
            float bi = b0[c], al = a0[c];
#pragma unroll
            for (int r = 0; r < 4; ++r) {
                float v = acc[t][r] + bi;
                v = v >= 0.f ? v : al * v;
                myt[(q * 4 + r) * TPAD + c] = f2b(v);
            }
        }
    }
    {
#pragma unroll
        for (int t = 0; t < 8; ++t) acc[t] = (f32x4){0.f, 0.f, 0.f, 0.f};
#pragma unroll
        for (int k = 0; k < HID; k += 32) {
            short8 a = *(const short8*)(const void*)(&myt[ln * TPAD + k + q * 8]);
#pragma unroll
            for (int t = 0; t < 8; ++t) {
                short8 b = *(const short8*)(const void*)(W1t + (size_t)(t * 16 + ln) * HID + k + q * 8);
                acc[t] = __builtin_amdgcn_mfma_f32_16x16x32_bf16(a, b, acc[t], 0, 0, 0);
            }
        }
#pragma unroll
        for (int t = 0; t < 8; ++t) {
            int c = t * 16 + ln;
            float bi = b1[c], al = a1[c];
#pragma unroll
            for (int r = 0; r < 4; ++r) {
                float v = acc[t][r] + bi;
                v = v >= 0.f ? v : al * v;
                myt[(q * 4 + r) * TPAD + c] = f2b(v);
            }
        }
    }
    {
#pragma unroll
        for (int t = 0; t < 8; ++t) acc[t] = (f32x4){0.f, 0.f, 0.f, 0.f};
#pragma unroll
        for (int k = 0; k < HID; k += 32) {
            short8 a = *(const short8*)(const void*)(&myt[ln * TPAD + k + q * 8]);
#pragma unroll
            for (int t = 0; t < 8; ++t) {
                short8 b = *(const short8*)(const void*)(W2t + (size_t)(t * 16 + ln) * HID + k + q * 8);
                acc[t] = __builtin_amdgcn_mfma_f32_16x16x32_bf16(a, b, acc[t], 0, 0, 0);
            }
        }
#pragma unroll
        for (int t = 0; t < 8; ++t) {
            int c = t * 16 + ln;
            float bi = b2[c];
#pragma unroll
            for (int r = 0; r < 4; ++r) {
                int mr = m0 + q * 4 + r;
                if (mr < M) outp[(size_t)mr * HID + c] = f2b(acc[t][r] + bi);
            }
        }
    }
}

// ---------------- GAT aggregation: fp8 xw rows (512 B), wave = node ----------------
__global__ __launch_bounds__(256) void k_gat_agg(
        const unsigned char* __restrict__ xw8, const float* __restrict__ es,
        const float* __restrict__ ed, const int* __restrict__ row_off,
        const int* __restrict__ col, const float* __restrict__ bias,
        const float* __restrict__ bng, const float* __restrict__ bnb,
        const float* __restrict__ bnm, const float* __restrict__ bnv,
        const float* __restrict__ pa,
        bf16* __restrict__ out) {
    __shared__ __align__(16) float sEx[4][MAXC4][HEADS];
    __shared__ int sCol[4][MAXC4];
    int w = threadIdx.x >> 6;
    int lane = threadIdx.x & 63;
    int i = blockIdx.x * 4 + w;          // grid = N/4 exactly
    int h = lane >> 4;
    const uint2*  xw2 = (const uint2*)xw8;    // row = 64 uint2 (512 B)
    const float4* es4 = (const float4*)es;
    float4 edi = ((const float4*)ed)[i];

    int s0 = row_off[i], s1 = row_off[i + 1];
    float den0 = 0.f, den1 = 0.f, den2 = 0.f, den3 = 0.f;
    float a[8];
#pragma unroll
    for (int j = 0; j < 8; ++j) a[j] = 0.f;

    {   // self loop
        float4 ev = es4[i];
        float e0 = ev.x + edi.x; e0 = e0 >= 0.f ? e0 : SLOPE * e0; float x0 = expf(e0);
        float e1 = ev.y + edi.y; e1 = e1 >= 0.f ? e1 : SLOPE * e1; float x1 = expf(e1);
        float e2 = ev.z + edi.z; e2 = e2 >= 0.f ? e2 : SLOPE * e2; float x2 = expf(e2);
        float e3 = ev.w + edi.w; e3 = e3 >= 0.f ? e3 : SLOPE * e3; float x3 = expf(e3);
        if (lane == 0) { den0 = x0; den1 = x1; den2 = x2; den3 = x3; }
        float ex = h == 0 ? x0 : h == 1 ? x1 : h == 2 ? x2 : x3;
        uint2 v = xw2[(size_t)i * 64 + lane];
        f32x2 p0 = __builtin_amdgcn_cvt_pk_f32_fp8((int)v.x, false);
        f32x2 p1 = __builtin_amdgcn_cvt_pk_f32_fp8((int)v.x, true);
        f32x2 p2 = __builtin_amdgcn_cvt_pk_f32_fp8((int)v.y, false);
        f32x2 p3 = __builtin_amdgcn_cvt_pk_f32_fp8((int)v.y, true);
        a[0] += ex * p0.x; a[1] += ex * p0.y;
        a[2] += ex * p1.x; a[3] += ex * p1.y;
        a[4] += ex * p2.x; a[5] += ex * p2.y;
        a[6] += ex * p3.x; a[7] += ex * p3.y;
    }
    for (int c0 = s0; c0 < s1; c0 += MAXC4) {
        int cnt = min(MAXC4, s1 - c0);
        if (lane < cnt) {
            int s = col[c0 + lane];
            float4 ev = es4[s];
            float e0 = ev.x + edi.x; e0 = e0 >= 0.f ? e0 : SLOPE * e0; float x0 = expf(e0);
            float e1 = ev.y + edi.y; e1 = e1 >= 0.f ? e1 : SLOPE * e1; float x1 = expf(e1);
            float e2 = ev.z + edi.z; e2 = e2 >= 0.f ? e2 : SLOPE * e2; float x2 = expf(e2);
            float e3 = ev.w + edi.w; e3 = e3 >= 0.f ? e3 : SLOPE * e3; float x3 = expf(e3);
            den0 += x0; den1 += x1; den2 += x2; den3 += x3;
            sCol[w][lane] = s;
            f32x4 xv = {x0, x1, x2, x3};
            *(f32x4*)(&sEx[w][lane][0]) = xv;
        }
        // same-wave LDS write->read: program order, no block barrier needed
        for (int e = 0; e < cnt; ++e) {
            float ex = sEx[w][e][h];
            int s = sCol[w][e];
            uint2 v = xw2[(size_t)s * 64 + lane];
            f32x2 p0 = __builtin_amdgcn_cvt_pk_f32_fp8((int)v.x, false);
            f32x2 p1 = __builtin_amdgcn_cvt_pk_f32_fp8((int)v.x, true);
            f32x2 p2 = __builtin_amdgcn_cvt_pk_f32_fp8((int)v.y, false);
            f32x2 p3 = __builtin_amdgcn_cvt_pk_f32_fp8((int)v.y, true);
            a[0] += ex * p0.x; a[1] += ex * p0.y;
            a[2] += ex * p1.x; a[3] += ex * p1.y;
            a[4] += ex * p2.x; a[5] += ex * p2.y;
            a[6] += ex * p3.x; a[7] += ex * p3.y;
        }
    }
    for (int off = 1; off < 64; off <<= 1) {
        den0 += __shfl_xor(den0, off, 64);
        den1 += __shfl_xor(den1, off, 64);
        den2 += __shfl_xor(den2, off, 64);
        den3 += __shfl_xor(den3, off, 64);
    }
    float den = h == 0 ? den0 : h == 1 ? den1 : h == 2 ? den2 : den3;
    float inv = 1.0f / den;
    float m[8];
#pragma unroll
    for (int j = 0; j < 8; ++j) m[j] = a[j] * inv;
#pragma unroll
    for (int j = 0; j < 8; ++j) {
        m[j] += __shfl_xor(m[j], 16, 64);
        m[j] += __shfl_xor(m[j], 32, 64);
    }
    if (lane < 16) {
        int cb = lane * 8;
        float r[8];
#pragma unroll
        for (int j = 0; j < 8; ++j) {
            int c = cb + j;
            float v = FP8SI * m[j] + bias[c];   // 0.25 head-mean * 1/16 fp8 scale
            v = (v - bnm[c]) * rsqrtf(bnv[c] + EPSB) * bng[c] + bnb[c];
            float al = pa[c];
            r[j] = v >= 0.f ? v : al * v;
        }
        uint4 o;
        o.x = packbf(r[0], r[1]); o.y = packbf(r[2], r[3]);
        o.z = packbf(r[4], r[5]); o.w = packbf(r[6], r[7]);
        ((uint4*)out)[(size_t)i * 16 + lane] = o;
    }
}

// ---------------- pool / classifier ----------------
__global__ void k_pool(const bf16* __restrict__ h, const int* __restrict__ gstart,
                       float* __restrict__ pool) {
    int g = blockIdx.x, s = blockIdx.y;
    int c = threadIdx.x;   // 64 lanes, channels 2c,2c+1
    int b0 = gstart[g], b1 = gstart[g + 1];
    int len = b1 - b0;
    if (len <= 0) return;
    int per = (len + PSEG - 1) / PSEG;
    int r0 = b0 + s * per;
    int r1 = min(r0 + per, b1);
    if (r0 >= r1) return;
    const unsigned* hb = (const unsigned*)h;
    float a0 = 0.f, a1 = 0.f;
    for (int i = r0; i < r1; ++i) {
        unsigned v = hb[(size_t)i * (HID / 2) + c];
        a0 += lo_f(v); a1 += hi_f(v);
    }
    atomicAdd(&pool[g * HID + 2 * c], a0);
    atomicAdd(&pool[g * HID + 2 * c + 1], a1);
}

__global__ void k_cls(const float* __restrict__ pool, const int* __restrict__ gstart,
                      const float* __restrict__ W, const float* __restrict__ b,
                      float* __restrict__ out) {
    int t = threadIdx.x;            // 512 = 64*8
    int g = t / NCLS, n = t % NCLS;
    float ic = 1.0f / fmaxf((float)(gstart[g + 1] - gstart[g]), 1.0f);
    float acc = b[n];
    for (int k = 0; k < HID; ++k)
        acc += pool[g * HID + k] * ic * W[k * NCLS + n];
    out[g * NCLS + n] = acc;
}

// ---------------- launch ----------------
extern "C" void kernel_launch(void* const* d_in, const int* in_sizes, int n_in,
                              void* d_out, int out_size, void* d_ws, size_t ws_size,
                              hipStream_t stream) {
    const float* x      = (const float*)d_in[0];
    const int*   ei     = (const int*)d_in[1];
    const int*   batch  = (const int*)d_in[2];
    const float* s0_Wl  = (const float*)d_in[3];
    const float* s0_Wr  = (const float*)d_in[4];
    const float* s0_b   = (const float*)d_in[5];
    const float* s1_Wl  = (const float*)d_in[6];
    const float* s1_Wr  = (const float*)d_in[7];
    const float* s1_b   = (const float*)d_in[8];
    const float* bn_g   = (const float*)d_in[9];
    const float* bn_b   = (const float*)d_in[10];
    const float* bn_m   = (const float*)d_in[11];
    const float* bn_v   = (const float*)d_in[12];
    const float* pre_a  = (const float*)d_in[13];
    const float* g0_W   = (const float*)d_in[14];
    const float* g0_as  = (const float*)d_in[15];
    const float* g0_ad  = (const float*)d_in[16];
    const float* g0_bias= (const float*)d_in[17];
    const float* g1_W   = (const float*)d_in[18];
    const float* g1_as  = (const float*)d_in[19];
    const float* g1_ad  = (const float*)d_in[20];
    const float* g1_bias= (const float*)d_in[21];
    const float* idp_W  = (const float*)d_in[22];
    const float* idp_b  = (const float*)d_in[23];
    const float* idp_a  = (const float*)d_in[24];
    const float* cls_W  = (const float*)d_in[25];
    const float* cls_b  = (const float*)d_in[26];
    float* out = (float*)d_out;

    // workspace carve (256B aligned)
    char* p = (char*)d_ws;
    auto alloc = [&](size_t bytes) -> void* {
        void* r = (void*)p;
        p += (bytes + 255) & ~(size_t)255;
        return r;
    };
    int*   degcur  = (int*)alloc((size_t)2 * N_NODES * 4);   // deg | cursor (one memset)
    int*   deg     = degcur;
    int*   cursor  = degcur + N_NODES;
    int*   row_off = (int*)alloc((size_t)(N_NODES + 1) * 4);
    int*   col     = (int*)alloc((size_t)N_EDGES * 4);
    int*   gstart  = (int*)alloc((size_t)(NGRAPH + 1) * 4);
    int*   bsum    = (int*)alloc((size_t)SCB * 4);
    int*   boff    = (int*)alloc((size_t)SCB * 4);
    float* es      = (float*)alloc((size_t)N_NODES * HEADS * 4);
    float* edv     = (float*)alloc((size_t)N_NODES * HEADS * 4);
    float* pool    = (float*)alloc((size_t)NGRAPH * HID * 4);
    bf16*  hA      = (bf16*)alloc((size_t)MPAD * HID * 2);
    bf16*  hB      = (bf16*)alloc((size_t)MPAD * HID * 2);
    // union: acat0 (MPAD*128 bf16=256B/row), acat1 (MPAD*256 bf16=512B/row), xw8 (MPAD*512 fp8)
    void*  u       = alloc((size_t)MPAD * 512);
    bf16*  acat0   = (bf16*)u;
    bf16*  acat1   = (bf16*)u;
    unsigned char* xw8 = (unsigned char*)u;
    // bf16 transposed weights
    bf16*  s0t     = (bf16*)alloc((size_t)128 * 128 * 2);
    bf16*  s1t     = (bf16*)alloc((size_t)128 * 256 * 2);
    bf16*  g0t     = (bf16*)alloc((size_t)512 * 128 * 2);
    bf16*  g1t     = (bf16*)alloc((size_t)512 * 128 * 2);
    bf16*  idpt    = (bf16*)alloc((size_t)3 * 128 * 128 * 2);

    hipMemsetAsync(degcur, 0, (size_t)2 * N_NODES * 4, stream);
    hipMemsetAsync(pool, 0, (size_t)NGRAPH * HID * 4, stream);

    // weight prep + CSR build + graph bounds
    k_prep<<<(229376 + 255) / 256, 256, 0, stream>>>(s0_Wl, s0_Wr, s1_Wl, s1_Wr,
                                                     g0_W, g1_W, idp_W,
                                                     s0t, s1t, g0t, g1t, idpt);
    k_count_bounds<<<(N_EDGES + 255) / 256, 256, 0, stream>>>(ei, deg, batch, gstart);
    k_scan1<<<NSB, SCB, 0, stream>>>(deg, row_off, bsum);
    k_scan2<<<1, SCB, 0, stream>>>(bsum, boff);
    k_scan3<<<(N_NODES + 255) / 256, 256, 0, stream>>>(row_off, boff);
    k_fill<<<(N_EDGES + 255) / 256, 256, 0, stream>>>(ei, row_off, cursor, col);

    const int MB = (N_NODES + 63) / 64;   // 782 row-blocks

    // SAGE 0
    k_sage_agg_f32<<<N_NODES / 4, 256, 0, stream>>>(x, row_off, col, acat0);
    k_gemm<128, 8, 1><<<dim3(MB, 1), 256, 0, stream>>>(
        acat0, s0t, hA, N_NODES, HID,
        s0_b, bn_g + 0 * HID, bn_b + 0 * HID, bn_m + 0 * HID, bn_v + 0 * HID, pre_a + 0 * HID,
        nullptr, nullptr, nullptr, nullptr);

    // SAGE 1
    k_sage_agg_bf<<<N_NODES / 4, 256, 0, stream>>>(hA, row_off, col, acat1);
    k_gemm<256, 8, 1><<<dim3(MB, 1), 256, 0, stream>>>(
        acat1, s1t, hB, N_NODES, HID,
        s1_b, bn_g + 1 * HID, bn_b + 1 * HID, bn_m + 1 * HID, bn_v + 1 * HID, pre_a + 1 * HID,
        nullptr, nullptr, nullptr, nullptr);

    // GAT 0 (gemm stores fp8 xw + fuses score computation)
    k_gemm<128, 8, 4><<<dim3(MB, 4), 256, 0, stream>>>(
        hB, g0t, xw8, N_NODES, HEADS * HID,
        nullptr, nullptr, nullptr, nullptr, nullptr, nullptr,
        g0_as, g0_ad, es, edv);
    k_gat_agg<<<N_NODES / 4, 256, 0, stream>>>(
        xw8, es, edv, row_off, col, g0_bias,
        bn_g + 2 * HID, bn_b + 2 * HID, bn_m + 2 * HID, bn_v + 2 * HID, pre_a + 2 * HID, hA);

    // GAT 1
    k_gemm<128, 8, 4><<<dim3(MB, 4), 256, 0, stream>>>(
        hA, g1t, xw8, N_NODES, HEADS * HID,
        nullptr, nullptr, nullptr, nullptr, nullptr, nullptr,
        g1_as, g1_ad, es, edv);
    k_gat_agg<<<N_NODES / 4, 256, 0, stream>>>(
        xw8, es, edv, row_off, col, g1_bias,
        bn_g + 3 * HID, bn_b + 3 * HID, bn_m + 3 * HID, bn_v + 3 * HID, pre_a + 3 * HID, hB);

    // IDP MLP (3 layers fused)
    k_mlp3<<<MB, 256, 0, stream>>>(
        hB, idpt + 0 * 16384, idpt + 1 * 16384, idpt + 2 * 16384,
        idp_b + 0 * HID, idp_a + 0 * HID,
        idp_b + 1 * HID, idp_a + 1 * HID,
        idp_b + 2 * HID, hA, N_NODES);

    // global mean pool + classifier
    k_pool<<<dim3(NGRAPH, PSEG), 64, 0, stream>>>(hA, gstart, pool);
    k_cls<<<1, NGRAPH * NCLS, 0, stream>>>(pool, gstart, cls_W, cls_b, out);
}